// Round 12
// baseline (585.064 us; speedup 1.0000x reference)
//
#include <hip/hip_runtime.h>
#include <hip/hip_bf16.h>
#include <stdint.h>

#define FDIM 128
#define CDIM 10

typedef unsigned short u16;
typedef unsigned char u8;
typedef __attribute__((ext_vector_type(8))) short short8;   // 8 bf16 (4 VGPRs) — MFMA A/B frag
typedef __attribute__((ext_vector_type(4))) float f32x4;    // MFMA C/D frag
typedef __attribute__((ext_vector_type(2))) float f32x2;

__device__ inline u16 f2bf(float f) {
    unsigned int u = __float_as_uint(f);
    u += 0x7fff + ((u >> 16) & 1);  // round-to-nearest-even
    return (u16)(u >> 16);
}
__device__ inline unsigned int pack2(float a, float b) {
    return (unsigned int)f2bf(a) | ((unsigned int)f2bf(b) << 16);
}
// accumulate 4 fp8 (one uint) into two f32x2 accs via hw cvt
__device__ inline void acc_fp8x4(f32x2& a0, f32x2& a1, unsigned u) {
    a0 += __builtin_amdgcn_cvt_pk_f32_fp8(u, false);
    a1 += __builtin_amdgcn_cvt_pk_f32_fp8(u, true);
}
// pack 4 f32 -> 4 fp8 bytes (one uint)
__device__ inline unsigned pk_fp8x4(float a, float b, float c, float d) {
    unsigned o = 0;
    o = __builtin_amdgcn_cvt_pk_fp8_f32(a, b, o, false);
    o = __builtin_amdgcn_cvt_pk_fp8_f32(c, d, o, true);
    return o;
}

// ---------------- utility ----------------

__global__ void sentinel_kernel(float* __restrict__ out, int n, float val) {
    int i = blockIdx.x * blockDim.x + threadIdx.x;
    if (i < n) out[i] = val;
}

// blocks 0..191: W[128][128] fp32 -> WbT[n][k] bf16 for 3 matrices
// block 192: zero row N of fp8 table + dbin; block 193: zero bcnt
__global__ void wconv_kernel(const float* __restrict__ W1, const float* __restrict__ W2,
                             const float* __restrict__ W3, u16* __restrict__ wbt,
                             unsigned* __restrict__ hs8A_rowN, int* __restrict__ dbin,
                             int* __restrict__ bcnt, int NB) {
    int tid = threadIdx.x;
    if (blockIdx.x == 192) {
        if (tid < FDIM / 4) hs8A_rowN[tid] = 0;
        if (tid < 256) dbin[tid] = 0;
        return;
    }
    if (blockIdx.x == 193) {
        for (int i = tid; i < NB; i += 256) bcnt[i] = 0;
        return;
    }
    int which = blockIdx.x >> 6;
    int i = (blockIdx.x & 63) * 256 + tid;
    const float* W = which == 0 ? W1 : (which == 1 ? W2 : W3);
    int k = i >> 7, n = i & 127;
    wbt[(size_t)which * 16384 + n * 128 + k] = f2bf(W[k * 128 + n]);
}

// x fp32 -> fp8 pre-scaled by dinv (4 elems/thread)
__global__ void xconv_kernel(const float* __restrict__ x, const float* __restrict__ dinv,
                             u8* __restrict__ hs8A, int N) {
    int i = (blockIdx.x * blockDim.x + threadIdx.x) * 4;
    if (i < N * FDIM) {
        int v = i >> 7;
        float dv = dinv[v];
        float4 f = *(const float4*)&x[i];
        ((unsigned*)hs8A)[i >> 2] = pk_fp8x4(dv * f.x, dv * f.y, dv * f.z, dv * f.w);
    }
}

// ---------------- bucketed CSR build (128-node buckets) ----------------
// b = dst >> 7.  NB = ceil(N/128) <= 1024.
// ebuf entry packed: (dst & 127) << 25 | src   (requires N <= 2^25)

#define ECHUNK 2048

__global__ __launch_bounds__(256) void count_kernel(const int* __restrict__ dst, int E,
                                                    int* __restrict__ bcnt, int NB) {
    __shared__ int lc[1024];
    int tid = threadIdx.x;
    for (int i = tid; i < NB; i += 256) lc[i] = 0;
    __syncthreads();
    int base = blockIdx.x * ECHUNK;
    int lim = min(base + ECHUNK, E);
    for (int i = base + tid; i < lim; i += 256)
        atomicAdd(&lc[dst[i] >> 7], 1);
    __syncthreads();
    for (int i = tid; i < NB; i += 256)
        if (lc[i]) atomicAdd(&bcnt[i], lc[i]);
}

__global__ __launch_bounds__(1024) void scan_kernel(const int* __restrict__ bcnt, int NB, int E,
                                                    int* __restrict__ boff, int* __restrict__ bcursor) {
    __shared__ int s[1024];
    int tid = threadIdx.x;
    s[tid] = (tid < NB) ? bcnt[tid] : 0;
    __syncthreads();
    for (int off = 1; off < 1024; off <<= 1) {
        int v = (tid >= off) ? s[tid - off] : 0;
        __syncthreads();
        s[tid] += v;
        __syncthreads();
    }
    int excl = tid ? s[tid - 1] : 0;
    if (tid < NB) { boff[tid] = excl; bcursor[tid] = excl; }
    if (tid == 0) boff[NB] = E;
}

__global__ __launch_bounds__(256) void part_kernel(const int* __restrict__ src,
                                                   const int* __restrict__ dst, int E,
                                                   int* __restrict__ bcursor,
                                                   unsigned* __restrict__ ebuf, int NB) {
    __shared__ int lc[1024];
    __shared__ int lbase[1024];
    int tid = threadIdx.x;
    for (int i = tid; i < NB; i += 256) lc[i] = 0;
    __syncthreads();
    int base = blockIdx.x * ECHUNK;
    int lim = min(base + ECHUNK, E);
    for (int i = base + tid; i < lim; i += 256)
        atomicAdd(&lc[dst[i] >> 7], 1);
    __syncthreads();
    for (int i = tid; i < NB; i += 256) {
        int c = lc[i];
        lbase[i] = c ? atomicAdd(&bcursor[i], c) : 0;
        lc[i] = 0;  // reuse as local cursor
    }
    __syncthreads();
    for (int i = base + tid; i < lim; i += 256) {
        int s_ = src[i];
        int d_ = dst[i];
        int b = d_ >> 7;
        int r = atomicAdd(&lc[b], 1);
        ebuf[lbase[b] + r] = ((unsigned)(d_ & 127) << 25) | (unsigned)s_;
    }
}

// one block per 128-node bucket: hist -> scan -> rowp/dinv; scatter colx; degree histogram -> dbin
__global__ __launch_bounds__(256) void build_kernel(const unsigned* __restrict__ ebuf,
                                                    const int* __restrict__ boff,
                                                    int* __restrict__ rowp, float* __restrict__ dinv,
                                                    int* __restrict__ colx, int* __restrict__ dbin,
                                                    int N, int E) {
    __shared__ int hist[128];
    __shared__ int pfx[128];
    __shared__ int cur[128];
    __shared__ int ldbin[256];
    int b = blockIdx.x;
    int tid = threadIdx.x;
    int ebase = boff[b], eend = boff[b + 1];
    if (tid < 128) hist[tid] = 0;
    ldbin[tid] = 0;
    __syncthreads();
    for (int i = ebase + tid; i < eend; i += 256)
        atomicAdd(&hist[ebuf[i] >> 25], 1);
    __syncthreads();
    if (tid < 128) pfx[tid] = hist[tid];
    __syncthreads();
    for (int off = 1; off < 128; off <<= 1) {
        int t = 0;
        if (tid < 128 && tid >= off) t = pfx[tid - off];
        __syncthreads();
        if (tid < 128) pfx[tid] += t;
        __syncthreads();
    }
    if (tid < 128) {
        int deg = hist[tid];
        int excl = pfx[tid] - deg;
        int node = b * 128 + tid;
        if (node < N) {
            rowp[node] = ebase + excl;
            dinv[node] = rsqrtf(1.0f + (float)deg);  // +1 self-loop
            if (node == N - 1) rowp[N] = E;
            atomicAdd(&ldbin[min(deg, 255)], 1);
        }
        cur[tid] = ebase + excl;
    }
    __syncthreads();
    for (int i = ebase + tid; i < eend; i += 256) {
        unsigned e = ebuf[i];
        int r = atomicAdd(&cur[e >> 25], 1);
        colx[r] = (int)(e & 0x1FFFFFFu);
    }
    if (ldbin[tid]) atomicAdd(&dbin[tid], ldbin[tid]);
}

// exclusive scan of dbin[256] -> dcur (base cursor per degree bin)
__global__ __launch_bounds__(256) void dscan_kernel(const int* __restrict__ dbin,
                                                    int* __restrict__ dcur) {
    __shared__ int s[256];
    int tid = threadIdx.x;
    s[tid] = dbin[tid];
    __syncthreads();
    for (int off = 1; off < 256; off <<= 1) {
        int v = (tid >= off) ? s[tid - off] : 0;
        __syncthreads();
        s[tid] += v;
        __syncthreads();
    }
    dcur[tid] = tid ? s[tid - 1] : 0;
}

// scatter nodes into degree-sorted permutation
__global__ __launch_bounds__(256) void dscatter_kernel(const int* __restrict__ rowp,
                                                       int* __restrict__ dcur,
                                                       int* __restrict__ perm, int N) {
    int i = blockIdx.x * blockDim.x + threadIdx.x;
    if (i < N) {
        int deg = rowp[i + 1] - rowp[i];
        int slot = atomicAdd(&dcur[min(deg, 255)], 1);
        perm[slot] = i;
    }
}

// ---------------- aggregation: node-per-group, degree-sorted order ----------------
// lane = 8*g + c: group g owns node v = perm[blk*32 + wave*8 + g]; its 8 lanes cover the
// 128-fp8 row (16B each). Group walks its own edge list (unroll 2); accumulate f32;
// out8[v] = fp8(dinv[v]*(hs8[v] + sum_u hs8[u])).

__global__ __launch_bounds__(256) void agg_kernel(const u8* __restrict__ hs8,
                                                  const float* __restrict__ dinv,
                                                  const int* __restrict__ rowp,
                                                  const int* __restrict__ colx,
                                                  const int* __restrict__ perm,
                                                  u8* __restrict__ out8, int N) {
    int tid = threadIdx.x;
    int lane = tid & 63;
    int g = lane >> 3;   // 0..7: node slot
    int c = lane & 7;    // 0..7: 16B chunk within row
    int idx = blockIdx.x * 32 + (tid >> 6) * 8 + g;
    bool valid = idx < N;
    int v = valid ? perm[idx] : N;

    const uint4* h4 = (const uint4*)hs8;  // row = 8 uint4
    f32x2 acc[8];
    uint4 s = h4[(size_t)v * 8 + c];      // v==N -> zero row (safe)
#pragma unroll
    for (int j = 0; j < 8; ++j) acc[j] = (f32x2){0.f, 0.f};
    acc_fp8x4(acc[0], acc[1], s.x); acc_fp8x4(acc[2], acc[3], s.y);
    acc_fp8x4(acc[4], acc[5], s.z); acc_fp8x4(acc[6], acc[7], s.w);

    int e = valid ? rowp[v] : 0;
    int end = valid ? rowp[v + 1] : 0;
    for (; e + 2 <= end; e += 2) {
        int u0 = colx[e];
        int u1 = colx[e + 1];
        uint4 r0 = h4[(size_t)u0 * 8 + c];
        uint4 r1 = h4[(size_t)u1 * 8 + c];
        acc_fp8x4(acc[0], acc[1], r0.x); acc_fp8x4(acc[2], acc[3], r0.y);
        acc_fp8x4(acc[4], acc[5], r0.z); acc_fp8x4(acc[6], acc[7], r0.w);
        acc_fp8x4(acc[0], acc[1], r1.x); acc_fp8x4(acc[2], acc[3], r1.y);
        acc_fp8x4(acc[4], acc[5], r1.z); acc_fp8x4(acc[6], acc[7], r1.w);
    }
    if (e < end) {
        int u = colx[e];
        uint4 r = h4[(size_t)u * 8 + c];
        acc_fp8x4(acc[0], acc[1], r.x); acc_fp8x4(acc[2], acc[3], r.y);
        acc_fp8x4(acc[4], acc[5], r.z); acc_fp8x4(acc[6], acc[7], r.w);
    }

    if (valid) {
        float dv = dinv[v];
        uint4 o;
        o.x = pk_fp8x4(dv * acc[0].x, dv * acc[0].y, dv * acc[1].x, dv * acc[1].y);
        o.y = pk_fp8x4(dv * acc[2].x, dv * acc[2].y, dv * acc[3].x, dv * acc[3].y);
        o.z = pk_fp8x4(dv * acc[4].x, dv * acc[4].y, dv * acc[5].x, dv * acc[5].y);
        o.w = pk_fp8x4(dv * acc[6].x, dv * acc[6].y, dv * acc[7].x, dv * acc[7].y);
        ((uint4*)out8)[(size_t)v * 8 + c] = o;
    }
}

// ---------------- MFMA GEMM: reads fp8 agg buffer; writes fp8 table (in-place safe:
// reads only in8) or bf16 h3 (layer 3). Single barrier; wave-local LDS afterwards. ----

template <bool FP8OUT>
__global__ __launch_bounds__(256) void gemm_mfma_kernel(const u8* __restrict__ in8,
                                                        const u16* __restrict__ WbT,
                                                        const float* __restrict__ bias,
                                                        const float* __restrict__ dinv,
                                                        u8* __restrict__ out8,
                                                        u16* __restrict__ outbf, int N) {
    __shared__ u16 As[64][136];
    __shared__ u8 As8[64][144];  // fp8 epilogue staging (wave-local rows only)
    int tid = threadIdx.x;
    int w = tid >> 6;
    int l = tid & 63;
    int row0 = blockIdx.x * 64;

    // stage A tile: 64 rows x 128 fp8 = 512 chunks of 16B; thread converts 2 -> bf16 LDS
#pragma unroll
    for (int i = 0; i < 2; ++i) {
        int ch = tid + 256 * i;
        int r = ch >> 3;
        int cc = ch & 7;
        uint4 val = make_uint4(0, 0, 0, 0);
        if (row0 + r < N) val = ((const uint4*)(in8 + (size_t)(row0 + r) * FDIM))[cc];
        f32x2 f0 = __builtin_amdgcn_cvt_pk_f32_fp8(val.x, false);
        f32x2 f1 = __builtin_amdgcn_cvt_pk_f32_fp8(val.x, true);
        f32x2 f2 = __builtin_amdgcn_cvt_pk_f32_fp8(val.y, false);
        f32x2 f3 = __builtin_amdgcn_cvt_pk_f32_fp8(val.y, true);
        f32x2 f4 = __builtin_amdgcn_cvt_pk_f32_fp8(val.z, false);
        f32x2 f5 = __builtin_amdgcn_cvt_pk_f32_fp8(val.z, true);
        f32x2 f6 = __builtin_amdgcn_cvt_pk_f32_fp8(val.w, false);
        f32x2 f7 = __builtin_amdgcn_cvt_pk_f32_fp8(val.w, true);
        uint4 o0, o1;
        o0.x = pack2(f0.x, f0.y); o0.y = pack2(f1.x, f1.y);
        o0.z = pack2(f2.x, f2.y); o0.w = pack2(f3.x, f3.y);
        o1.x = pack2(f4.x, f4.y); o1.y = pack2(f5.x, f5.y);
        o1.z = pack2(f6.x, f6.y); o1.w = pack2(f7.x, f7.y);
        *(uint4*)&As[r][cc * 16] = o0;
        *(uint4*)&As[r][cc * 16 + 8] = o1;
    }
    __syncthreads();  // the only barrier

    int arow = w * 16 + (l & 15);
    int kblk = (l >> 4) * 8;
    f32x4 facc[8];
#pragma unroll
    for (int f = 0; f < 8; ++f) facc[f] = (f32x4){0.f, 0.f, 0.f, 0.f};

#pragma unroll
    for (int kk = 0; kk < 4; ++kk) {
        int k0 = kk * 32 + kblk;
        short8 a = *(const short8*)&As[arow][k0];
#pragma unroll
        for (int f = 0; f < 8; ++f) {
            int col = f * 16 + (l & 15);
            short8 bfr = *(const short8*)&WbT[(size_t)col * FDIM + k0];
            facc[f] = __builtin_amdgcn_mfma_f32_16x16x32_bf16(a, bfr, facc[f], 0, 0, 0);
        }
    }

    int rbase = w * 16 + (l >> 4) * 4;
    int cidx = l & 15;

    if constexpr (FP8OUT) {
        float dvr[4];
#pragma unroll
        for (int r = 0; r < 4; ++r) {
            int row = row0 + rbase + r;
            dvr[r] = (row < N) ? dinv[row] : 1.f;
        }
#pragma unroll
        for (int f = 0; f < 8; ++f) {
            int col = f * 16 + cidx;
            float bv = bias[col];
#pragma unroll
            for (int r = 0; r < 4; ++r) {
                float val = dvr[r] * fmaxf(facc[f][r] + bv, 0.f);
                unsigned pk = __builtin_amdgcn_cvt_pk_fp8_f32(val, 0.f, 0, false);
                As8[rbase + r][col] = (u8)(pk & 0xff);
            }
        }
        // wave-local coalesced store: 16 rows x 128B = 2 iters x 64 lanes x 16B
#pragma unroll
        for (int i = 0; i < 2; ++i) {
            int flat = i * 64 + l;
            int r = w * 16 + (flat >> 3);
            int ch = flat & 7;
            if (row0 + r < N)
                ((uint4*)(out8 + (size_t)(row0 + r) * FDIM))[ch] = *(const uint4*)&As8[r][ch * 16];
        }
    } else {
        // epilogue: relu(acc+b) -> bf16 into As (wave-local), coalesced store to outbf
#pragma unroll
        for (int f = 0; f < 8; ++f) {
            int col = f * 16 + cidx;
            float bv = bias[col];
#pragma unroll
            for (int r = 0; r < 4; ++r)
                As[rbase + r][col] = f2bf(fmaxf(facc[f][r] + bv, 0.f));
        }
#pragma unroll
        for (int i = 0; i < 4; ++i) {
            int r = w * 16 + (l >> 4) * 4 + i;
            int col = (l & 15) * 8;
            if (row0 + r < N) *(uint4*)&outbf[(size_t)(row0 + r) * FDIM + col] = *(const uint4*)&As[r][col];
        }
    }
}

// ---------------- pooling + classifier head + log_softmax ----------------

__global__ __launch_bounds__(512) void pool_head_kernel(const u16* __restrict__ h,
                                                        const int* __restrict__ batch, int N,
                                                        const float* __restrict__ Wo,
                                                        const float* __restrict__ bo,
                                                        float* __restrict__ out, int G) {
    int g = blockIdx.x;
    int tid = threadIdx.x;
    __shared__ int bounds[2];
    __shared__ float2 red[512];
    __shared__ float sp[128];
    __shared__ float lg[CDIM];
    __shared__ float sm[2];

    if (tid < 2) {
        int target = g + tid;
        int lo = 0, hi = N;
        while (lo < hi) {
            int mid = (lo + hi) >> 1;
            if (batch[mid] < target) lo = mid + 1; else hi = mid;
        }
        bounds[tid] = lo;
    }
    __syncthreads();
    int lo = bounds[0], hi = bounds[1];
    int cnt = hi - lo;

    int j = tid & 63;
    int rg = tid >> 6;
    const unsigned* h2 = (const unsigned*)h;
    float ax = 0.f, ay = 0.f;
    for (int r = lo + rg; r < hi; r += 8) {
        unsigned u = h2[(size_t)r * 64 + j];
        ax += __uint_as_float(u << 16);
        ay += __uint_as_float(u & 0xffff0000u);
    }
    red[tid] = make_float2(ax, ay);
    __syncthreads();
    if (tid < 64) {
        float sx = 0.f, sy = 0.f;
#pragma unroll
        for (int k = 0; k < 8; ++k) {
            float2 t = red[tid + 64 * k];
            sx += t.x; sy += t.y;
        }
        float inv = 1.f / (float)max(cnt, 1);
        sp[2 * tid] = sx * inv;
        sp[2 * tid + 1] = sy * inv;
    }
    __syncthreads();

    if (tid < CDIM) {
        float l = bo[tid];
        for (int k = 0; k < 128; ++k) l += sp[k] * Wo[(size_t)k * CDIM + tid];
        lg[tid] = l;
    }
    __syncthreads();
    if (tid == 0) {
        float m = -1e30f;
        for (int c = 0; c < CDIM; ++c) m = fmaxf(m, lg[c]);
        float ssum = 0.f;
        for (int c = 0; c < CDIM; ++c) ssum += expf(lg[c] - m);
        sm[0] = m;
        sm[1] = logf(ssum);
    }
    __syncthreads();
    if (tid < CDIM) out[(size_t)g * CDIM + tid] = lg[tid] - sm[0] - sm[1];
}

// ---------------- launch ----------------

extern "C" void kernel_launch(void* const* d_in, const int* in_sizes, int n_in,
                              void* d_out, int out_size, void* d_ws, size_t ws_size,
                              hipStream_t stream) {
    const float* x = (const float*)d_in[0];
    const int* edge = (const int*)d_in[1];      // int32 (harness converts integer inputs)
    const int* batch = (const int*)d_in[2];     // int32
    const float* W1 = (const float*)d_in[4];
    const float* b1 = (const float*)d_in[5];
    const float* W2 = (const float*)d_in[6];
    const float* b2 = (const float*)d_in[7];
    const float* W3 = (const float*)d_in[8];
    const float* b3 = (const float*)d_in[9];
    const float* Wo = (const float*)d_in[10];
    const float* bo = (const float*)d_in[11];

    int N = in_sizes[2];
    int E = in_sizes[1] / 2;
    int G = out_size / CDIM;
    const int* src = edge;
    const int* dst = edge + E;
    int NB = (N + 127) >> 7;   // 128-node buckets

    size_t off = 0;
    auto carve = [&](size_t bytes) -> size_t {
        size_t r = off;
        off += (bytes + 255) & ~(size_t)255;
        return r;
    };
    size_t o_h3   = carve((size_t)N * FDIM * 2);          // bf16 h3 (ebuf aliases here)
    size_t o_hs8A = carve((size_t)(N + 1) * FDIM);        // fp8 gather table (row N = zeros)
    size_t o_agg8 = carve((size_t)N * FDIM);              // fp8 agg output
    size_t o_colx = carve((size_t)E * 4);
    size_t o_rowp = carve((size_t)(N + 1) * 4);
    size_t o_dinv = carve((size_t)N * 4);
    size_t o_perm = carve((size_t)N * 4);
    size_t o_bcnt = carve((size_t)NB * 4);
    size_t o_boff = carve((size_t)(NB + 1) * 4);
    size_t o_bcur = carve((size_t)NB * 4);
    size_t o_dbin = carve(256 * 4);
    size_t o_dcur = carve(256 * 4);
    size_t o_wbt  = carve((size_t)3 * 16384 * 2);

    bool ok = off <= ws_size && NB <= 1024 && N <= (1 << 25) &&
              (size_t)E * 4 <= (size_t)N * FDIM * 2;  // packed ebuf fits in h3 alias
    if (!ok) {
        sentinel_kernel<<<(out_size + 255) / 256, 256, 0, stream>>>((float*)d_out, out_size, 1234.5f);
        return;
    }

    char* base = (char*)d_ws;
    u16* h3bf  = (u16*)(base + o_h3);
    u8* hs8A   = (u8*)(base + o_hs8A);
    u8* agg8   = (u8*)(base + o_agg8);
    unsigned* ebuf = (unsigned*)(base + o_h3);  // alias: dead after build_kernel; h3 written by L3 gemm
    int* colx  = (int*)(base + o_colx);
    int* rowp  = (int*)(base + o_rowp);
    float* dinv = (float*)(base + o_dinv);
    int* perm  = (int*)(base + o_perm);
    int* bcnt  = (int*)(base + o_bcnt);
    int* boff  = (int*)(base + o_boff);
    int* bcur  = (int*)(base + o_bcur);
    int* dbin  = (int*)(base + o_dbin);
    int* dcur  = (int*)(base + o_dcur);
    u16* wbt   = (u16*)(base + o_wbt);

    int nchunk = (E + ECHUNK - 1) / ECHUNK;

    wconv_kernel<<<194, 256, 0, stream>>>(W1, W2, W3, wbt,
                                          (unsigned*)(hs8A + (size_t)N * FDIM), dbin, bcnt, NB);
    count_kernel<<<nchunk, 256, 0, stream>>>(dst, E, bcnt, NB);
    scan_kernel<<<1, 1024, 0, stream>>>(bcnt, NB, E, boff, bcur);
    part_kernel<<<nchunk, 256, 0, stream>>>(src, dst, E, bcur, ebuf, NB);
    build_kernel<<<NB, 256, 0, stream>>>(ebuf, boff, rowp, dinv, colx, dbin, N, E);
    dscan_kernel<<<1, 256, 0, stream>>>(dbin, dcur);
    dscatter_kernel<<<(N + 255) / 256, 256, 0, stream>>>(rowp, dcur, perm, N);
    xconv_kernel<<<(N * FDIM / 4 + 255) / 256, 256, 0, stream>>>(x, dinv, hs8A, N);

    int aggBlocks = (N + 31) / 32;
    int gemmBlocks = (N + 63) / 64;

    // L1: gather hs8A -> agg8; gemm reads agg8 -> overwrites hs8A (next table)
    agg_kernel<<<aggBlocks, 256, 0, stream>>>(hs8A, dinv, rowp, colx, perm, agg8, N);
    gemm_mfma_kernel<true><<<gemmBlocks, 256, 0, stream>>>(agg8, wbt, b1, dinv, hs8A, nullptr, N);
    // L2
    agg_kernel<<<aggBlocks, 256, 0, stream>>>(hs8A, dinv, rowp, colx, perm, agg8, N);
    gemm_mfma_kernel<true><<<gemmBlocks, 256, 0, stream>>>(agg8, wbt + 16384, b2, dinv, hs8A, nullptr, N);
    // L3: gather -> agg8; gemm -> bf16 h3
    agg_kernel<<<aggBlocks, 256, 0, stream>>>(hs8A, dinv, rowp, colx, perm, agg8, N);
    gemm_mfma_kernel<false><<<gemmBlocks, 256, 0, stream>>>(agg8, wbt + 32768, b3, dinv, nullptr, h3bf, N);

    pool_head_kernel<<<G, 512, 0, stream>>>(h3bf, batch, N, Wo, bo, (float*)d_out, G);
}

// Round 13
// 331.420 us; speedup vs baseline: 1.7653x; 1.7653x over previous
//
#include <hip/hip_runtime.h>
#include <hip/hip_bf16.h>
#include <stdint.h>

#define FDIM 128
#define CDIM 10

typedef unsigned short u16;
typedef unsigned char u8;
typedef __attribute__((ext_vector_type(8))) short short8;   // 8 bf16 (4 VGPRs) — MFMA A/B frag
typedef __attribute__((ext_vector_type(4))) float f32x4;    // MFMA C/D frag
typedef __attribute__((ext_vector_type(2))) float f32x2;

__device__ inline u16 f2bf(float f) {
    unsigned int u = __float_as_uint(f);
    u += 0x7fff + ((u >> 16) & 1);  // round-to-nearest-even
    return (u16)(u >> 16);
}
__device__ inline unsigned int pack2(float a, float b) {
    return (unsigned int)f2bf(a) | ((unsigned int)f2bf(b) << 16);
}
// accumulate 4 fp8 (one uint) into two f32x2 accs via hw cvt
__device__ inline void acc_fp8x4(f32x2& a0, f32x2& a1, unsigned u) {
    a0 += __builtin_amdgcn_cvt_pk_f32_fp8(u, false);
    a1 += __builtin_amdgcn_cvt_pk_f32_fp8(u, true);
}
// pack 4 f32 -> 4 fp8 bytes (one uint)
__device__ inline unsigned pk_fp8x4(float a, float b, float c, float d) {
    unsigned o = 0;
    o = __builtin_amdgcn_cvt_pk_fp8_f32(a, b, o, false);
    o = __builtin_amdgcn_cvt_pk_fp8_f32(c, d, o, true);
    return o;
}

// ---------------- utility ----------------

__global__ void sentinel_kernel(float* __restrict__ out, int n, float val) {
    int i = blockIdx.x * blockDim.x + threadIdx.x;
    if (i < n) out[i] = val;
}

// blocks 0..191: W[128][128] fp32 -> WbT[n][k] bf16 for 3 matrices
// block 192: zero row N of fp8 table + dbin; block 193: zero bcnt
__global__ void wconv_kernel(const float* __restrict__ W1, const float* __restrict__ W2,
                             const float* __restrict__ W3, u16* __restrict__ wbt,
                             unsigned* __restrict__ hs8A_rowN, int* __restrict__ dbin,
                             int* __restrict__ bcnt, int NB) {
    int tid = threadIdx.x;
    if (blockIdx.x == 192) {
        if (tid < FDIM / 4) hs8A_rowN[tid] = 0;
        if (tid < 256) dbin[tid] = 0;
        return;
    }
    if (blockIdx.x == 193) {
        for (int i = tid; i < NB; i += 256) bcnt[i] = 0;
        return;
    }
    int which = blockIdx.x >> 6;
    int i = (blockIdx.x & 63) * 256 + tid;
    const float* W = which == 0 ? W1 : (which == 1 ? W2 : W3);
    int k = i >> 7, n = i & 127;
    wbt[(size_t)which * 16384 + n * 128 + k] = f2bf(W[k * 128 + n]);
}

// x fp32 -> fp8 pre-scaled by dinv (4 elems/thread)
__global__ void xconv_kernel(const float* __restrict__ x, const float* __restrict__ dinv,
                             u8* __restrict__ hs8A, int N) {
    int i = (blockIdx.x * blockDim.x + threadIdx.x) * 4;
    if (i < N * FDIM) {
        int v = i >> 7;
        float dv = dinv[v];
        float4 f = *(const float4*)&x[i];
        ((unsigned*)hs8A)[i >> 2] = pk_fp8x4(dv * f.x, dv * f.y, dv * f.z, dv * f.w);
    }
}

// ---------------- bucketed CSR build (128-node buckets) ----------------
// b = dst >> 7.  NB = ceil(N/128) <= 1024.
// ebuf entry packed: (dst & 127) << 25 | src   (requires N <= 2^25)

#define ECHUNK 2048

__global__ __launch_bounds__(256) void count_kernel(const int* __restrict__ dst, int E,
                                                    int* __restrict__ bcnt, int NB) {
    __shared__ int lc[1024];
    int tid = threadIdx.x;
    for (int i = tid; i < NB; i += 256) lc[i] = 0;
    __syncthreads();
    int base = blockIdx.x * ECHUNK;
    int lim = min(base + ECHUNK, E);
    for (int i = base + tid; i < lim; i += 256)
        atomicAdd(&lc[dst[i] >> 7], 1);
    __syncthreads();
    for (int i = tid; i < NB; i += 256)
        if (lc[i]) atomicAdd(&bcnt[i], lc[i]);
}

__global__ __launch_bounds__(1024) void scan_kernel(const int* __restrict__ bcnt, int NB, int E,
                                                    int* __restrict__ boff, int* __restrict__ bcursor) {
    __shared__ int s[1024];
    int tid = threadIdx.x;
    s[tid] = (tid < NB) ? bcnt[tid] : 0;
    __syncthreads();
    for (int off = 1; off < 1024; off <<= 1) {
        int v = (tid >= off) ? s[tid - off] : 0;
        __syncthreads();
        s[tid] += v;
        __syncthreads();
    }
    int excl = tid ? s[tid - 1] : 0;
    if (tid < NB) { boff[tid] = excl; bcursor[tid] = excl; }
    if (tid == 0) boff[NB] = E;
}

__global__ __launch_bounds__(256) void part_kernel(const int* __restrict__ src,
                                                   const int* __restrict__ dst, int E,
                                                   int* __restrict__ bcursor,
                                                   unsigned* __restrict__ ebuf, int NB) {
    __shared__ int lc[1024];
    __shared__ int lbase[1024];
    int tid = threadIdx.x;
    for (int i = tid; i < NB; i += 256) lc[i] = 0;
    __syncthreads();
    int base = blockIdx.x * ECHUNK;
    int lim = min(base + ECHUNK, E);
    for (int i = base + tid; i < lim; i += 256)
        atomicAdd(&lc[dst[i] >> 7], 1);
    __syncthreads();
    for (int i = tid; i < NB; i += 256) {
        int c = lc[i];
        lbase[i] = c ? atomicAdd(&bcursor[i], c) : 0;
        lc[i] = 0;  // reuse as local cursor
    }
    __syncthreads();
    for (int i = base + tid; i < lim; i += 256) {
        int s_ = src[i];
        int d_ = dst[i];
        int b = d_ >> 7;
        int r = atomicAdd(&lc[b], 1);
        ebuf[lbase[b] + r] = ((unsigned)(d_ & 127) << 25) | (unsigned)s_;
    }
}

// one block per 128-node bucket: hist -> scan -> rowp/dinv; scatter colx; degree histogram -> dbin
__global__ __launch_bounds__(256) void build_kernel(const unsigned* __restrict__ ebuf,
                                                    const int* __restrict__ boff,
                                                    int* __restrict__ rowp, float* __restrict__ dinv,
                                                    int* __restrict__ colx, int* __restrict__ dbin,
                                                    int N, int E) {
    __shared__ int hist[128];
    __shared__ int pfx[128];
    __shared__ int cur[128];
    __shared__ int ldbin[256];
    int b = blockIdx.x;
    int tid = threadIdx.x;
    int ebase = boff[b], eend = boff[b + 1];
    if (tid < 128) hist[tid] = 0;
    ldbin[tid] = 0;
    __syncthreads();
    for (int i = ebase + tid; i < eend; i += 256)
        atomicAdd(&hist[ebuf[i] >> 25], 1);
    __syncthreads();
    if (tid < 128) pfx[tid] = hist[tid];
    __syncthreads();
    for (int off = 1; off < 128; off <<= 1) {
        int t = 0;
        if (tid < 128 && tid >= off) t = pfx[tid - off];
        __syncthreads();
        if (tid < 128) pfx[tid] += t;
        __syncthreads();
    }
    if (tid < 128) {
        int deg = hist[tid];
        int excl = pfx[tid] - deg;
        int node = b * 128 + tid;
        if (node < N) {
            rowp[node] = ebase + excl;
            dinv[node] = rsqrtf(1.0f + (float)deg);  // +1 self-loop
            if (node == N - 1) rowp[N] = E;
            atomicAdd(&ldbin[min(deg, 255)], 1);
        }
        cur[tid] = ebase + excl;
    }
    __syncthreads();
    for (int i = ebase + tid; i < eend; i += 256) {
        unsigned e = ebuf[i];
        int r = atomicAdd(&cur[e >> 25], 1);
        colx[r] = (int)(e & 0x1FFFFFFu);
    }
    if (ldbin[tid]) atomicAdd(&dbin[tid], ldbin[tid]);
}

// exclusive scan of dbin[256] -> dcur (base cursor per degree bin)
__global__ __launch_bounds__(256) void dscan_kernel(const int* __restrict__ dbin,
                                                    int* __restrict__ dcur) {
    __shared__ int s[256];
    int tid = threadIdx.x;
    s[tid] = dbin[tid];
    __syncthreads();
    for (int off = 1; off < 256; off <<= 1) {
        int v = (tid >= off) ? s[tid - off] : 0;
        __syncthreads();
        s[tid] += v;
        __syncthreads();
    }
    dcur[tid] = tid ? s[tid - 1] : 0;
}

// contention-free degree-sorted permutation: one block per 128 nodes.
// LDS bin counts + ranks; ONE atomicAdd per (block, nonzero bin) to reserve global base.
__global__ __launch_bounds__(128) void dscatter_kernel(const int* __restrict__ rowp,
                                                       int* __restrict__ dcur,
                                                       int* __restrict__ perm, int N) {
    __shared__ int lbin[256];
    __shared__ int lbase[256];
    int b = blockIdx.x;
    int tid = threadIdx.x;
    lbin[tid] = 0;
    lbin[tid + 128] = 0;
    __syncthreads();
    int node = b * 128 + tid;
    int bin = 0, rank = 0;
    bool valid = node < N;
    if (valid) {
        bin = min(rowp[node + 1] - rowp[node], 255);
        rank = atomicAdd(&lbin[bin], 1);
    }
    __syncthreads();
    int c0 = lbin[tid];
    int c1 = lbin[tid + 128];
    lbase[tid] = c0 ? atomicAdd(&dcur[tid], c0) : 0;
    lbase[tid + 128] = c1 ? atomicAdd(&dcur[tid + 128], c1) : 0;
    __syncthreads();
    if (valid) perm[lbase[bin] + rank] = node;
}

// ---------------- aggregation: node-per-group, degree-sorted order ----------------
// lane = 8*g + c: group g owns node v = perm[blk*32 + wave*8 + g]; its 8 lanes cover the
// 128-fp8 row (16B each). Group walks its own edge list (unroll 2); accumulate f32;
// out8[v] = fp8(dinv[v]*(hs8[v] + sum_u hs8[u])).

__global__ __launch_bounds__(256) void agg_kernel(const u8* __restrict__ hs8,
                                                  const float* __restrict__ dinv,
                                                  const int* __restrict__ rowp,
                                                  const int* __restrict__ colx,
                                                  const int* __restrict__ perm,
                                                  u8* __restrict__ out8, int N) {
    int tid = threadIdx.x;
    int lane = tid & 63;
    int g = lane >> 3;   // 0..7: node slot
    int c = lane & 7;    // 0..7: 16B chunk within row
    int idx = blockIdx.x * 32 + (tid >> 6) * 8 + g;
    bool valid = idx < N;
    int v = valid ? perm[idx] : N;

    const uint4* h4 = (const uint4*)hs8;  // row = 8 uint4
    f32x2 acc[8];
    uint4 s = h4[(size_t)v * 8 + c];      // v==N -> zero row (safe)
#pragma unroll
    for (int j = 0; j < 8; ++j) acc[j] = (f32x2){0.f, 0.f};
    acc_fp8x4(acc[0], acc[1], s.x); acc_fp8x4(acc[2], acc[3], s.y);
    acc_fp8x4(acc[4], acc[5], s.z); acc_fp8x4(acc[6], acc[7], s.w);

    int e = valid ? rowp[v] : 0;
    int end = valid ? rowp[v + 1] : 0;
    for (; e + 2 <= end; e += 2) {
        int u0 = colx[e];
        int u1 = colx[e + 1];
        uint4 r0 = h4[(size_t)u0 * 8 + c];
        uint4 r1 = h4[(size_t)u1 * 8 + c];
        acc_fp8x4(acc[0], acc[1], r0.x); acc_fp8x4(acc[2], acc[3], r0.y);
        acc_fp8x4(acc[4], acc[5], r0.z); acc_fp8x4(acc[6], acc[7], r0.w);
        acc_fp8x4(acc[0], acc[1], r1.x); acc_fp8x4(acc[2], acc[3], r1.y);
        acc_fp8x4(acc[4], acc[5], r1.z); acc_fp8x4(acc[6], acc[7], r1.w);
    }
    if (e < end) {
        int u = colx[e];
        uint4 r = h4[(size_t)u * 8 + c];
        acc_fp8x4(acc[0], acc[1], r.x); acc_fp8x4(acc[2], acc[3], r.y);
        acc_fp8x4(acc[4], acc[5], r.z); acc_fp8x4(acc[6], acc[7], r.w);
    }

    if (valid) {
        float dv = dinv[v];
        uint4 o;
        o.x = pk_fp8x4(dv * acc[0].x, dv * acc[0].y, dv * acc[1].x, dv * acc[1].y);
        o.y = pk_fp8x4(dv * acc[2].x, dv * acc[2].y, dv * acc[3].x, dv * acc[3].y);
        o.z = pk_fp8x4(dv * acc[4].x, dv * acc[4].y, dv * acc[5].x, dv * acc[5].y);
        o.w = pk_fp8x4(dv * acc[6].x, dv * acc[6].y, dv * acc[7].x, dv * acc[7].y);
        ((uint4*)out8)[(size_t)v * 8 + c] = o;
    }
}

// ---------------- MFMA GEMM: reads fp8 agg buffer; writes fp8 table (in-place safe:
// reads only in8) or bf16 h3 (layer 3). Single barrier; wave-local LDS afterwards. ----

template <bool FP8OUT>
__global__ __launch_bounds__(256) void gemm_mfma_kernel(const u8* __restrict__ in8,
                                                        const u16* __restrict__ WbT,
                                                        const float* __restrict__ bias,
                                                        const float* __restrict__ dinv,
                                                        u8* __restrict__ out8,
                                                        u16* __restrict__ outbf, int N) {
    __shared__ u16 As[64][136];
    __shared__ u8 As8[64][144];  // fp8 epilogue staging (wave-local rows only)
    int tid = threadIdx.x;
    int w = tid >> 6;
    int l = tid & 63;
    int row0 = blockIdx.x * 64;

    // stage A tile: 64 rows x 128 fp8 = 512 chunks of 16B; thread converts 2 -> bf16 LDS
#pragma unroll
    for (int i = 0; i < 2; ++i) {
        int ch = tid + 256 * i;
        int r = ch >> 3;
        int cc = ch & 7;
        uint4 val = make_uint4(0, 0, 0, 0);
        if (row0 + r < N) val = ((const uint4*)(in8 + (size_t)(row0 + r) * FDIM))[cc];
        f32x2 f0 = __builtin_amdgcn_cvt_pk_f32_fp8(val.x, false);
        f32x2 f1 = __builtin_amdgcn_cvt_pk_f32_fp8(val.x, true);
        f32x2 f2 = __builtin_amdgcn_cvt_pk_f32_fp8(val.y, false);
        f32x2 f3 = __builtin_amdgcn_cvt_pk_f32_fp8(val.y, true);
        f32x2 f4 = __builtin_amdgcn_cvt_pk_f32_fp8(val.z, false);
        f32x2 f5 = __builtin_amdgcn_cvt_pk_f32_fp8(val.z, true);
        f32x2 f6 = __builtin_amdgcn_cvt_pk_f32_fp8(val.w, false);
        f32x2 f7 = __builtin_amdgcn_cvt_pk_f32_fp8(val.w, true);
        uint4 o0, o1;
        o0.x = pack2(f0.x, f0.y); o0.y = pack2(f1.x, f1.y);
        o0.z = pack2(f2.x, f2.y); o0.w = pack2(f3.x, f3.y);
        o1.x = pack2(f4.x, f4.y); o1.y = pack2(f5.x, f5.y);
        o1.z = pack2(f6.x, f6.y); o1.w = pack2(f7.x, f7.y);
        *(uint4*)&As[r][cc * 16] = o0;
        *(uint4*)&As[r][cc * 16 + 8] = o1;
    }
    __syncthreads();  // the only barrier

    int arow = w * 16 + (l & 15);
    int kblk = (l >> 4) * 8;
    f32x4 facc[8];
#pragma unroll
    for (int f = 0; f < 8; ++f) facc[f] = (f32x4){0.f, 0.f, 0.f, 0.f};

#pragma unroll
    for (int kk = 0; kk < 4; ++kk) {
        int k0 = kk * 32 + kblk;
        short8 a = *(const short8*)&As[arow][k0];
#pragma unroll
        for (int f = 0; f < 8; ++f) {
            int col = f * 16 + (l & 15);
            short8 bfr = *(const short8*)&WbT[(size_t)col * FDIM + k0];
            facc[f] = __builtin_amdgcn_mfma_f32_16x16x32_bf16(a, bfr, facc[f], 0, 0, 0);
        }
    }

    int rbase = w * 16 + (l >> 4) * 4;
    int cidx = l & 15;

    if constexpr (FP8OUT) {
        float dvr[4];
#pragma unroll
        for (int r = 0; r < 4; ++r) {
            int row = row0 + rbase + r;
            dvr[r] = (row < N) ? dinv[row] : 1.f;
        }
#pragma unroll
        for (int f = 0; f < 8; ++f) {
            int col = f * 16 + cidx;
            float bv = bias[col];
#pragma unroll
            for (int r = 0; r < 4; ++r) {
                float val = dvr[r] * fmaxf(facc[f][r] + bv, 0.f);
                unsigned pk = __builtin_amdgcn_cvt_pk_fp8_f32(val, 0.f, 0, false);
                As8[rbase + r][col] = (u8)(pk & 0xff);
            }
        }
        // wave-local coalesced store: 16 rows x 128B = 2 iters x 64 lanes x 16B
#pragma unroll
        for (int i = 0; i < 2; ++i) {
            int flat = i * 64 + l;
            int r = w * 16 + (flat >> 3);
            int ch = flat & 7;
            if (row0 + r < N)
                ((uint4*)(out8 + (size_t)(row0 + r) * FDIM))[ch] = *(const uint4*)&As8[r][ch * 16];
        }
    } else {
        // epilogue: relu(acc+b) -> bf16 into As (wave-local), coalesced store to outbf
#pragma unroll
        for (int f = 0; f < 8; ++f) {
            int col = f * 16 + cidx;
            float bv = bias[col];
#pragma unroll
            for (int r = 0; r < 4; ++r)
                As[rbase + r][col] = f2bf(fmaxf(facc[f][r] + bv, 0.f));
        }
#pragma unroll
        for (int i = 0; i < 4; ++i) {
            int r = w * 16 + (l >> 4) * 4 + i;
            int col = (l & 15) * 8;
            if (row0 + r < N) *(uint4*)&outbf[(size_t)(row0 + r) * FDIM + col] = *(const uint4*)&As[r][col];
        }
    }
}

// ---------------- pooling + classifier head + log_softmax ----------------

__global__ __launch_bounds__(512) void pool_head_kernel(const u16* __restrict__ h,
                                                        const int* __restrict__ batch, int N,
                                                        const float* __restrict__ Wo,
                                                        const float* __restrict__ bo,
                                                        float* __restrict__ out, int G) {
    int g = blockIdx.x;
    int tid = threadIdx.x;
    __shared__ int bounds[2];
    __shared__ float2 red[512];
    __shared__ float sp[128];
    __shared__ float lg[CDIM];
    __shared__ float sm[2];

    if (tid < 2) {
        int target = g + tid;
        int lo = 0, hi = N;
        while (lo < hi) {
            int mid = (lo + hi) >> 1;
            if (batch[mid] < target) lo = mid + 1; else hi = mid;
        }
        bounds[tid] = lo;
    }
    __syncthreads();
    int lo = bounds[0], hi = bounds[1];
    int cnt = hi - lo;

    int j = tid & 63;
    int rg = tid >> 6;
    const unsigned* h2 = (const unsigned*)h;
    float ax = 0.f, ay = 0.f;
    for (int r = lo + rg; r < hi; r += 8) {
        unsigned u = h2[(size_t)r * 64 + j];
        ax += __uint_as_float(u << 16);
        ay += __uint_as_float(u & 0xffff0000u);
    }
    red[tid] = make_float2(ax, ay);
    __syncthreads();
    if (tid < 64) {
        float sx = 0.f, sy = 0.f;
#pragma unroll
        for (int k = 0; k < 8; ++k) {
            float2 t = red[tid + 64 * k];
            sx += t.x; sy += t.y;
        }
        float inv = 1.f / (float)max(cnt, 1);
        sp[2 * tid] = sx * inv;
        sp[2 * tid + 1] = sy * inv;
    }
    __syncthreads();

    if (tid < CDIM) {
        float l = bo[tid];
        for (int k = 0; k < 128; ++k) l += sp[k] * Wo[(size_t)k * CDIM + tid];
        lg[tid] = l;
    }
    __syncthreads();
    if (tid == 0) {
        float m = -1e30f;
        for (int c = 0; c < CDIM; ++c) m = fmaxf(m, lg[c]);
        float ssum = 0.f;
        for (int c = 0; c < CDIM; ++c) ssum += expf(lg[c] - m);
        sm[0] = m;
        sm[1] = logf(ssum);
    }
    __syncthreads();
    if (tid < CDIM) out[(size_t)g * CDIM + tid] = lg[tid] - sm[0] - sm[1];
}

// ---------------- launch ----------------

extern "C" void kernel_launch(void* const* d_in, const int* in_sizes, int n_in,
                              void* d_out, int out_size, void* d_ws, size_t ws_size,
                              hipStream_t stream) {
    const float* x = (const float*)d_in[0];
    const int* edge = (const int*)d_in[1];      // int32 (harness converts integer inputs)
    const int* batch = (const int*)d_in[2];     // int32
    const float* W1 = (const float*)d_in[4];
    const float* b1 = (const float*)d_in[5];
    const float* W2 = (const float*)d_in[6];
    const float* b2 = (const float*)d_in[7];
    const float* W3 = (const float*)d_in[8];
    const float* b3 = (const float*)d_in[9];
    const float* Wo = (const float*)d_in[10];
    const float* bo = (const float*)d_in[11];

    int N = in_sizes[2];
    int E = in_sizes[1] / 2;
    int G = out_size / CDIM;
    const int* src = edge;
    const int* dst = edge + E;
    int NB = (N + 127) >> 7;   // 128-node buckets

    size_t off = 0;
    auto carve = [&](size_t bytes) -> size_t {
        size_t r = off;
        off += (bytes + 255) & ~(size_t)255;
        return r;
    };
    size_t o_h3   = carve((size_t)N * FDIM * 2);          // bf16 h3 (ebuf aliases here)
    size_t o_hs8A = carve((size_t)(N + 1) * FDIM);        // fp8 gather table (row N = zeros)
    size_t o_agg8 = carve((size_t)N * FDIM);              // fp8 agg output
    size_t o_colx = carve((size_t)E * 4);
    size_t o_rowp = carve((size_t)(N + 1) * 4);
    size_t o_dinv = carve((size_t)N * 4);
    size_t o_perm = carve((size_t)N * 4);
    size_t o_bcnt = carve((size_t)NB * 4);
    size_t o_boff = carve((size_t)(NB + 1) * 4);
    size_t o_bcur = carve((size_t)NB * 4);
    size_t o_dbin = carve(256 * 4);
    size_t o_dcur = carve(256 * 4);
    size_t o_wbt  = carve((size_t)3 * 16384 * 2);

    bool ok = off <= ws_size && NB <= 1024 && N <= (1 << 25) &&
              (size_t)E * 4 <= (size_t)N * FDIM * 2;  // packed ebuf fits in h3 alias
    if (!ok) {
        sentinel_kernel<<<(out_size + 255) / 256, 256, 0, stream>>>((float*)d_out, out_size, 1234.5f);
        return;
    }

    char* base = (char*)d_ws;
    u16* h3bf  = (u16*)(base + o_h3);
    u8* hs8A   = (u8*)(base + o_hs8A);
    u8* agg8   = (u8*)(base + o_agg8);
    unsigned* ebuf = (unsigned*)(base + o_h3);  // alias: dead after build_kernel; h3 written by L3 gemm
    int* colx  = (int*)(base + o_colx);
    int* rowp  = (int*)(base + o_rowp);
    float* dinv = (float*)(base + o_dinv);
    int* perm  = (int*)(base + o_perm);
    int* bcnt  = (int*)(base + o_bcnt);
    int* boff  = (int*)(base + o_boff);
    int* bcur  = (int*)(base + o_bcur);
    int* dbin  = (int*)(base + o_dbin);
    int* dcur  = (int*)(base + o_dcur);
    u16* wbt   = (u16*)(base + o_wbt);

    int nchunk = (E + ECHUNK - 1) / ECHUNK;

    wconv_kernel<<<194, 256, 0, stream>>>(W1, W2, W3, wbt,
                                          (unsigned*)(hs8A + (size_t)N * FDIM), dbin, bcnt, NB);
    count_kernel<<<nchunk, 256, 0, stream>>>(dst, E, bcnt, NB);
    scan_kernel<<<1, 1024, 0, stream>>>(bcnt, NB, E, boff, bcur);
    part_kernel<<<nchunk, 256, 0, stream>>>(src, dst, E, bcur, ebuf, NB);
    build_kernel<<<NB, 256, 0, stream>>>(ebuf, boff, rowp, dinv, colx, dbin, N, E);
    dscan_kernel<<<1, 256, 0, stream>>>(dbin, dcur);
    dscatter_kernel<<<NB, 128, 0, stream>>>(rowp, dcur, perm, N);
    xconv_kernel<<<(N * FDIM / 4 + 255) / 256, 256, 0, stream>>>(x, dinv, hs8A, N);

    int aggBlocks = (N + 31) / 32;
    int gemmBlocks = (N + 63) / 64;

    // L1: gather hs8A -> agg8; gemm reads agg8 -> overwrites hs8A (next table)
    agg_kernel<<<aggBlocks, 256, 0, stream>>>(hs8A, dinv, rowp, colx, perm, agg8, N);
    gemm_mfma_kernel<true><<<gemmBlocks, 256, 0, stream>>>(agg8, wbt, b1, dinv, hs8A, nullptr, N);
    // L2
    agg_kernel<<<aggBlocks, 256, 0, stream>>>(hs8A, dinv, rowp, colx, perm, agg8, N);
    gemm_mfma_kernel<true><<<gemmBlocks, 256, 0, stream>>>(agg8, wbt + 16384, b2, dinv, hs8A, nullptr, N);
    // L3: gather -> agg8; gemm -> bf16 h3
    agg_kernel<<<aggBlocks, 256, 0, stream>>>(hs8A, dinv, rowp, colx, perm, agg8, N);
    gemm_mfma_kernel<false><<<gemmBlocks, 256, 0, stream>>>(agg8, wbt + 32768, b3, dinv, nullptr, h3bf, N);

    pool_head_kernel<<<G, 512, 0, stream>>>(h3bf, batch, N, Wo, bo, (float*)d_out, G);
}

// Round 14
// 281.115 us; speedup vs baseline: 2.0812x; 1.1789x over previous
//
#include <hip/hip_runtime.h>
#include <hip/hip_bf16.h>
#include <stdint.h>

#define FDIM 128
#define CDIM 10

typedef unsigned short u16;
typedef unsigned char u8;
typedef __attribute__((ext_vector_type(8))) short short8;   // 8 bf16 (4 VGPRs) — MFMA A/B frag
typedef __attribute__((ext_vector_type(4))) float f32x4;    // MFMA C/D frag
typedef __attribute__((ext_vector_type(2))) float f32x2;

__device__ inline u16 f2bf(float f) {
    unsigned int u = __float_as_uint(f);
    u += 0x7fff + ((u >> 16) & 1);  // round-to-nearest-even
    return (u16)(u >> 16);
}
__device__ inline unsigned int pack2(float a, float b) {
    return (unsigned int)f2bf(a) | ((unsigned int)f2bf(b) << 16);
}
// accumulate 4 fp8 (one uint) into two f32x2 accs via hw cvt
__device__ inline void acc_fp8x4(f32x2& a0, f32x2& a1, unsigned u) {
    a0 += __builtin_amdgcn_cvt_pk_f32_fp8(u, false);
    a1 += __builtin_amdgcn_cvt_pk_f32_fp8(u, true);
}
// pack 4 f32 -> 4 fp8 bytes (one uint)
__device__ inline unsigned pk_fp8x4(float a, float b, float c, float d) {
    unsigned o = 0;
    o = __builtin_amdgcn_cvt_pk_fp8_f32(a, b, o, false);
    o = __builtin_amdgcn_cvt_pk_fp8_f32(c, d, o, true);
    return o;
}

// ---------------- utility ----------------

__global__ void sentinel_kernel(float* __restrict__ out, int n, float val) {
    int i = blockIdx.x * blockDim.x + threadIdx.x;
    if (i < n) out[i] = val;
}

// blocks 0..191: W[128][128] fp32 -> WbT[n][k] bf16 for 3 matrices
// block 192: zero row N of fp8 table; block 193: zero bcnt
__global__ void wconv_kernel(const float* __restrict__ W1, const float* __restrict__ W2,
                             const float* __restrict__ W3, u16* __restrict__ wbt,
                             unsigned* __restrict__ hs8A_rowN, int* __restrict__ bcnt, int NB) {
    int tid = threadIdx.x;
    if (blockIdx.x == 192) {
        if (tid < FDIM / 4) hs8A_rowN[tid] = 0;
        return;
    }
    if (blockIdx.x == 193) {
        for (int i = tid; i < NB; i += 256) bcnt[i] = 0;
        return;
    }
    int which = blockIdx.x >> 6;
    int i = (blockIdx.x & 63) * 256 + tid;
    const float* W = which == 0 ? W1 : (which == 1 ? W2 : W3);
    int k = i >> 7, n = i & 127;
    wbt[(size_t)which * 16384 + n * 128 + k] = f2bf(W[k * 128 + n]);
}

// x fp32 -> fp8 pre-scaled by dinv (4 elems/thread)
__global__ void xconv_kernel(const float* __restrict__ x, const float* __restrict__ dinv,
                             u8* __restrict__ hs8A, int N) {
    int i = (blockIdx.x * blockDim.x + threadIdx.x) * 4;
    if (i < N * FDIM) {
        int v = i >> 7;
        float dv = dinv[v];
        float4 f = *(const float4*)&x[i];
        ((unsigned*)hs8A)[i >> 2] = pk_fp8x4(dv * f.x, dv * f.y, dv * f.z, dv * f.w);
    }
}

// ---------------- bucketed CSR build (256-node buckets — R10 proven config) ----------------
// b = dst >> 8.  NB = ceil(N/256) <= 512.
// ebuf entry packed: (dst & 255) << 24 | src   (requires N <= 2^24)

#define ECHUNK 4096

__global__ __launch_bounds__(256) void count_kernel(const int* __restrict__ dst, int E,
                                                    int* __restrict__ bcnt, int NB) {
    __shared__ int lc[512];
    int tid = threadIdx.x;
    for (int i = tid; i < NB; i += 256) lc[i] = 0;
    __syncthreads();
    int base = blockIdx.x * ECHUNK;
    int lim = min(base + ECHUNK, E);
    for (int i = base + tid; i < lim; i += 256)
        atomicAdd(&lc[dst[i] >> 8], 1);
    __syncthreads();
    for (int i = tid; i < NB; i += 256)
        if (lc[i]) atomicAdd(&bcnt[i], lc[i]);
}

__global__ __launch_bounds__(512) void scan_kernel(const int* __restrict__ bcnt, int NB, int E,
                                                   int* __restrict__ boff, int* __restrict__ bcursor) {
    __shared__ int s[512];
    int tid = threadIdx.x;
    s[tid] = (tid < NB) ? bcnt[tid] : 0;
    __syncthreads();
    for (int off = 1; off < 512; off <<= 1) {
        int v = (tid >= off) ? s[tid - off] : 0;
        __syncthreads();
        s[tid] += v;
        __syncthreads();
    }
    int excl = tid ? s[tid - 1] : 0;
    if (tid < NB) { boff[tid] = excl; bcursor[tid] = excl; }
    if (tid == 0) boff[NB] = E;
}

__global__ __launch_bounds__(256) void part_kernel(const int* __restrict__ src,
                                                   const int* __restrict__ dst, int E,
                                                   int* __restrict__ bcursor,
                                                   unsigned* __restrict__ ebuf, int NB) {
    __shared__ int lc[512];
    __shared__ int lbase[512];
    int tid = threadIdx.x;
    for (int i = tid; i < NB; i += 256) lc[i] = 0;
    __syncthreads();
    int base = blockIdx.x * ECHUNK;
    int lim = min(base + ECHUNK, E);
    for (int i = base + tid; i < lim; i += 256)
        atomicAdd(&lc[dst[i] >> 8], 1);
    __syncthreads();
    for (int i = tid; i < NB; i += 256) {
        int c = lc[i];
        lbase[i] = c ? atomicAdd(&bcursor[i], c) : 0;
        lc[i] = 0;  // reuse as local cursor
    }
    __syncthreads();
    for (int i = base + tid; i < lim; i += 256) {
        int s_ = src[i];
        int d_ = dst[i];
        int b = d_ >> 8;
        int r = atomicAdd(&lc[b], 1);
        ebuf[lbase[b] + r] = ((unsigned)(d_ & 255) << 24) | (unsigned)s_;
    }
}

// one block per 256-node bucket: hist -> scan -> rowp/dinv; scatter colx in bucket window
__global__ __launch_bounds__(256) void build_kernel(const unsigned* __restrict__ ebuf,
                                                    const int* __restrict__ boff,
                                                    int* __restrict__ rowp, float* __restrict__ dinv,
                                                    int* __restrict__ colx, int N, int E) {
    __shared__ int hist[256];
    __shared__ int pfx[256];
    __shared__ int cur[256];
    int b = blockIdx.x;
    int tid = threadIdx.x;
    int ebase = boff[b], eend = boff[b + 1];
    hist[tid] = 0;
    __syncthreads();
    for (int i = ebase + tid; i < eend; i += 256)
        atomicAdd(&hist[ebuf[i] >> 24], 1);
    __syncthreads();
    int deg = hist[tid];
    pfx[tid] = deg;
    __syncthreads();
    for (int off = 1; off < 256; off <<= 1) {
        int t = (tid >= off) ? pfx[tid - off] : 0;
        __syncthreads();
        pfx[tid] += t;
        __syncthreads();
    }
    int excl = pfx[tid] - deg;
    int node = b * 256 + tid;
    if (node < N) {
        rowp[node] = ebase + excl;
        dinv[node] = rsqrtf(1.0f + (float)deg);  // +1 self-loop
        if (node == N - 1) rowp[N] = E;
    }
    cur[tid] = ebase + excl;
    __syncthreads();
    for (int i = ebase + tid; i < eend; i += 256) {
        unsigned e = ebuf[i];
        int r = atomicAdd(&cur[e >> 24], 1);
        colx[r] = (int)(e & 0xFFFFFFu);
    }
}

// ---------------- aggregation: node-per-group, unroll 4 (4 row-gathers in flight) ----------------
// lane = 8*g + c: group g owns node v = blk*32 + wave*8 + g; its 8 lanes cover the
// 128-fp8 row (16B each). Tail edges clamp to zero row N.
// out8[v] = fp8(dinv[v]*(hs8[v] + sum_u hs8[u])).

__global__ __launch_bounds__(256) void agg_kernel(const u8* __restrict__ hs8,
                                                  const float* __restrict__ dinv,
                                                  const int* __restrict__ rowp,
                                                  const int* __restrict__ colx,
                                                  u8* __restrict__ out8, int N) {
    int tid = threadIdx.x;
    int lane = tid & 63;
    int g = lane >> 3;   // 0..7: node slot
    int c = lane & 7;    // 0..7: 16B chunk within row
    int v = blockIdx.x * 32 + (tid >> 6) * 8 + g;
    bool valid = v < N;
    int vv = valid ? v : N;  // clamp to zero row

    const uint4* h4 = (const uint4*)hs8;  // row = 8 uint4
    f32x2 acc[8];
    uint4 s = h4[(size_t)vv * 8 + c];
#pragma unroll
    for (int j = 0; j < 8; ++j) acc[j] = (f32x2){0.f, 0.f};
    acc_fp8x4(acc[0], acc[1], s.x); acc_fp8x4(acc[2], acc[3], s.y);
    acc_fp8x4(acc[4], acc[5], s.z); acc_fp8x4(acc[6], acc[7], s.w);

    int e = valid ? rowp[v] : 0;
    int end = valid ? rowp[v + 1] : 0;
    for (; e < end; e += 4) {
        // clamped indices keep loads in-bounds; masked selects route tails to zero row N
        int i1 = min(e + 1, end - 1);
        int i2 = min(e + 2, end - 1);
        int i3 = min(e + 3, end - 1);
        int u0 = colx[e];
        int u1 = (e + 1 < end) ? colx[i1] : N;
        int u2 = (e + 2 < end) ? colx[i2] : N;
        int u3 = (e + 3 < end) ? colx[i3] : N;
        uint4 r0 = h4[(size_t)u0 * 8 + c];
        uint4 r1 = h4[(size_t)u1 * 8 + c];
        uint4 r2 = h4[(size_t)u2 * 8 + c];
        uint4 r3 = h4[(size_t)u3 * 8 + c];
        acc_fp8x4(acc[0], acc[1], r0.x); acc_fp8x4(acc[2], acc[3], r0.y);
        acc_fp8x4(acc[4], acc[5], r0.z); acc_fp8x4(acc[6], acc[7], r0.w);
        acc_fp8x4(acc[0], acc[1], r1.x); acc_fp8x4(acc[2], acc[3], r1.y);
        acc_fp8x4(acc[4], acc[5], r1.z); acc_fp8x4(acc[6], acc[7], r1.w);
        acc_fp8x4(acc[0], acc[1], r2.x); acc_fp8x4(acc[2], acc[3], r2.y);
        acc_fp8x4(acc[4], acc[5], r2.z); acc_fp8x4(acc[6], acc[7], r2.w);
        acc_fp8x4(acc[0], acc[1], r3.x); acc_fp8x4(acc[2], acc[3], r3.y);
        acc_fp8x4(acc[4], acc[5], r3.z); acc_fp8x4(acc[6], acc[7], r3.w);
    }

    if (valid) {
        float dv = dinv[v];
        uint4 o;
        o.x = pk_fp8x4(dv * acc[0].x, dv * acc[0].y, dv * acc[1].x, dv * acc[1].y);
        o.y = pk_fp8x4(dv * acc[2].x, dv * acc[2].y, dv * acc[3].x, dv * acc[3].y);
        o.z = pk_fp8x4(dv * acc[4].x, dv * acc[4].y, dv * acc[5].x, dv * acc[5].y);
        o.w = pk_fp8x4(dv * acc[6].x, dv * acc[6].y, dv * acc[7].x, dv * acc[7].y);
        ((uint4*)out8)[(size_t)v * 8 + c] = o;
    }
}

// ---------------- MFMA GEMM: reads fp8 agg buffer; writes fp8 table (in-place safe:
// reads only in8) or bf16 h3 (layer 3). Single barrier; wave-local LDS afterwards. ----

template <bool FP8OUT>
__global__ __launch_bounds__(256) void gemm_mfma_kernel(const u8* __restrict__ in8,
                                                        const u16* __restrict__ WbT,
                                                        const float* __restrict__ bias,
                                                        const float* __restrict__ dinv,
                                                        u8* __restrict__ out8,
                                                        u16* __restrict__ outbf, int N) {
    __shared__ u16 As[64][136];
    __shared__ u8 As8[64][144];  // fp8 epilogue staging (wave-local rows only)
    int tid = threadIdx.x;
    int w = tid >> 6;
    int l = tid & 63;
    int row0 = blockIdx.x * 64;

    // stage A tile: 64 rows x 128 fp8 = 512 chunks of 16B; thread converts 2 -> bf16 LDS
#pragma unroll
    for (int i = 0; i < 2; ++i) {
        int ch = tid + 256 * i;
        int r = ch >> 3;
        int cc = ch & 7;
        uint4 val = make_uint4(0, 0, 0, 0);
        if (row0 + r < N) val = ((const uint4*)(in8 + (size_t)(row0 + r) * FDIM))[cc];
        f32x2 f0 = __builtin_amdgcn_cvt_pk_f32_fp8(val.x, false);
        f32x2 f1 = __builtin_amdgcn_cvt_pk_f32_fp8(val.x, true);
        f32x2 f2 = __builtin_amdgcn_cvt_pk_f32_fp8(val.y, false);
        f32x2 f3 = __builtin_amdgcn_cvt_pk_f32_fp8(val.y, true);
        f32x2 f4 = __builtin_amdgcn_cvt_pk_f32_fp8(val.z, false);
        f32x2 f5 = __builtin_amdgcn_cvt_pk_f32_fp8(val.z, true);
        f32x2 f6 = __builtin_amdgcn_cvt_pk_f32_fp8(val.w, false);
        f32x2 f7 = __builtin_amdgcn_cvt_pk_f32_fp8(val.w, true);
        uint4 o0, o1;
        o0.x = pack2(f0.x, f0.y); o0.y = pack2(f1.x, f1.y);
        o0.z = pack2(f2.x, f2.y); o0.w = pack2(f3.x, f3.y);
        o1.x = pack2(f4.x, f4.y); o1.y = pack2(f5.x, f5.y);
        o1.z = pack2(f6.x, f6.y); o1.w = pack2(f7.x, f7.y);
        *(uint4*)&As[r][cc * 16] = o0;
        *(uint4*)&As[r][cc * 16 + 8] = o1;
    }
    __syncthreads();  // the only barrier

    int arow = w * 16 + (l & 15);
    int kblk = (l >> 4) * 8;
    f32x4 facc[8];
#pragma unroll
    for (int f = 0; f < 8; ++f) facc[f] = (f32x4){0.f, 0.f, 0.f, 0.f};

#pragma unroll
    for (int kk = 0; kk < 4; ++kk) {
        int k0 = kk * 32 + kblk;
        short8 a = *(const short8*)&As[arow][k0];
#pragma unroll
        for (int f = 0; f < 8; ++f) {
            int col = f * 16 + (l & 15);
            short8 bfr = *(const short8*)&WbT[(size_t)col * FDIM + k0];
            facc[f] = __builtin_amdgcn_mfma_f32_16x16x32_bf16(a, bfr, facc[f], 0, 0, 0);
        }
    }

    int rbase = w * 16 + (l >> 4) * 4;
    int cidx = l & 15;

    if constexpr (FP8OUT) {
        float dvr[4];
#pragma unroll
        for (int r = 0; r < 4; ++r) {
            int row = row0 + rbase + r;
            dvr[r] = (row < N) ? dinv[row] : 1.f;
        }
#pragma unroll
        for (int f = 0; f < 8; ++f) {
            int col = f * 16 + cidx;
            float bv = bias[col];
#pragma unroll
            for (int r = 0; r < 4; ++r) {
                float val = dvr[r] * fmaxf(facc[f][r] + bv, 0.f);
                unsigned pk = __builtin_amdgcn_cvt_pk_fp8_f32(val, 0.f, 0, false);
                As8[rbase + r][col] = (u8)(pk & 0xff);
            }
        }
        // wave-local coalesced store: 16 rows x 128B = 2 iters x 64 lanes x 16B
#pragma unroll
        for (int i = 0; i < 2; ++i) {
            int flat = i * 64 + l;
            int r = w * 16 + (flat >> 3);
            int ch = flat & 7;
            if (row0 + r < N)
                ((uint4*)(out8 + (size_t)(row0 + r) * FDIM))[ch] = *(const uint4*)&As8[r][ch * 16];
        }
    } else {
        // epilogue: relu(acc+b) -> bf16 into As (wave-local), coalesced store to outbf
#pragma unroll
        for (int f = 0; f < 8; ++f) {
            int col = f * 16 + cidx;
            float bv = bias[col];
#pragma unroll
            for (int r = 0; r < 4; ++r)
                As[rbase + r][col] = f2bf(fmaxf(facc[f][r] + bv, 0.f));
        }
#pragma unroll
        for (int i = 0; i < 4; ++i) {
            int r = w * 16 + (l >> 4) * 4 + i;
            int col = (l & 15) * 8;
            if (row0 + r < N) *(uint4*)&outbf[(size_t)(row0 + r) * FDIM + col] = *(const uint4*)&As[r][col];
        }
    }
}

// ---------------- pooling + classifier head + log_softmax ----------------

__global__ __launch_bounds__(512) void pool_head_kernel(const u16* __restrict__ h,
                                                        const int* __restrict__ batch, int N,
                                                        const float* __restrict__ Wo,
                                                        const float* __restrict__ bo,
                                                        float* __restrict__ out, int G) {
    int g = blockIdx.x;
    int tid = threadIdx.x;
    __shared__ int bounds[2];
    __shared__ float2 red[512];
    __shared__ float sp[128];
    __shared__ float lg[CDIM];
    __shared__ float sm[2];

    if (tid < 2) {
        int target = g + tid;
        int lo = 0, hi = N;
        while (lo < hi) {
            int mid = (lo + hi) >> 1;
            if (batch[mid] < target) lo = mid + 1; else hi = mid;
        }
        bounds[tid] = lo;
    }
    __syncthreads();
    int lo = bounds[0], hi = bounds[1];
    int cnt = hi - lo;

    int j = tid & 63;
    int rg = tid >> 6;
    const unsigned* h2 = (const unsigned*)h;
    float ax = 0.f, ay = 0.f;
    for (int r = lo + rg; r < hi; r += 8) {
        unsigned u = h2[(size_t)r * 64 + j];
        ax += __uint_as_float(u << 16);
        ay += __uint_as_float(u & 0xffff0000u);
    }
    red[tid] = make_float2(ax, ay);
    __syncthreads();
    if (tid < 64) {
        float sx = 0.f, sy = 0.f;
#pragma unroll
        for (int k = 0; k < 8; ++k) {
            float2 t = red[tid + 64 * k];
            sx += t.x; sy += t.y;
        }
        float inv = 1.f / (float)max(cnt, 1);
        sp[2 * tid] = sx * inv;
        sp[2 * tid + 1] = sy * inv;
    }
    __syncthreads();

    if (tid < CDIM) {
        float l = bo[tid];
        for (int k = 0; k < 128; ++k) l += sp[k] * Wo[(size_t)k * CDIM + tid];
        lg[tid] = l;
    }
    __syncthreads();
    if (tid == 0) {
        float m = -1e30f;
        for (int c = 0; c < CDIM; ++c) m = fmaxf(m, lg[c]);
        float ssum = 0.f;
        for (int c = 0; c < CDIM; ++c) ssum += expf(lg[c] - m);
        sm[0] = m;
        sm[1] = logf(ssum);
    }
    __syncthreads();
    if (tid < CDIM) out[(size_t)g * CDIM + tid] = lg[tid] - sm[0] - sm[1];
}

// ---------------- launch ----------------

extern "C" void kernel_launch(void* const* d_in, const int* in_sizes, int n_in,
                              void* d_out, int out_size, void* d_ws, size_t ws_size,
                              hipStream_t stream) {
    const float* x = (const float*)d_in[0];
    const int* edge = (const int*)d_in[1];      // int32 (harness converts integer inputs)
    const int* batch = (const int*)d_in[2];     // int32
    const float* W1 = (const float*)d_in[4];
    const float* b1 = (const float*)d_in[5];
    const float* W2 = (const float*)d_in[6];
    const float* b2 = (const float*)d_in[7];
    const float* W3 = (const float*)d_in[8];
    const float* b3 = (const float*)d_in[9];
    const float* Wo = (const float*)d_in[10];
    const float* bo = (const float*)d_in[11];

    int N = in_sizes[2];
    int E = in_sizes[1] / 2;
    int G = out_size / CDIM;
    const int* src = edge;
    const int* dst = edge + E;
    int NB = (N + 255) >> 8;   // 256-node buckets

    size_t off = 0;
    auto carve = [&](size_t bytes) -> size_t {
        size_t r = off;
        off += (bytes + 255) & ~(size_t)255;
        return r;
    };
    size_t o_h3   = carve((size_t)N * FDIM * 2);          // bf16 h3 (ebuf aliases here)
    size_t o_hs8A = carve((size_t)(N + 1) * FDIM);        // fp8 gather table (row N = zeros)
    size_t o_agg8 = carve((size_t)N * FDIM);              // fp8 agg output
    size_t o_colx = carve((size_t)E * 4);
    size_t o_rowp = carve((size_t)(N + 1) * 4);
    size_t o_dinv = carve((size_t)N * 4);
    size_t o_bcnt = carve((size_t)NB * 4);
    size_t o_boff = carve((size_t)(NB + 1) * 4);
    size_t o_bcur = carve((size_t)NB * 4);
    size_t o_wbt  = carve((size_t)3 * 16384 * 2);

    bool ok = off <= ws_size && NB <= 512 && N <= (1 << 24) &&
              (size_t)E * 4 <= (size_t)N * FDIM * 2;  // packed ebuf fits in h3 alias
    if (!ok) {
        sentinel_kernel<<<(out_size + 255) / 256, 256, 0, stream>>>((float*)d_out, out_size, 1234.5f);
        return;
    }

    char* base = (char*)d_ws;
    u16* h3bf  = (u16*)(base + o_h3);
    u8* hs8A   = (u8*)(base + o_hs8A);
    u8* agg8   = (u8*)(base + o_agg8);
    unsigned* ebuf = (unsigned*)(base + o_h3);  // alias: dead after build_kernel; h3 written by L3 gemm
    int* colx  = (int*)(base + o_colx);
    int* rowp  = (int*)(base + o_rowp);
    float* dinv = (float*)(base + o_dinv);
    int* bcnt  = (int*)(base + o_bcnt);
    int* boff  = (int*)(base + o_boff);
    int* bcur  = (int*)(base + o_bcur);
    u16* wbt   = (u16*)(base + o_wbt);

    int nchunk = (E + ECHUNK - 1) / ECHUNK;

    wconv_kernel<<<194, 256, 0, stream>>>(W1, W2, W3, wbt,
                                          (unsigned*)(hs8A + (size_t)N * FDIM), bcnt, NB);
    count_kernel<<<nchunk, 256, 0, stream>>>(dst, E, bcnt, NB);
    scan_kernel<<<1, 512, 0, stream>>>(bcnt, NB, E, boff, bcur);
    part_kernel<<<nchunk, 256, 0, stream>>>(src, dst, E, bcur, ebuf, NB);
    build_kernel<<<NB, 256, 0, stream>>>(ebuf, boff, rowp, dinv, colx, N, E);
    xconv_kernel<<<(N * FDIM / 4 + 255) / 256, 256, 0, stream>>>(x, dinv, hs8A, N);

    int aggBlocks = (N + 31) / 32;
    int gemmBlocks = (N + 63) / 64;

    // L1: gather hs8A -> agg8; gemm reads agg8 -> overwrites hs8A (next table)
    agg_kernel<<<aggBlocks, 256, 0, stream>>>(hs8A, dinv, rowp, colx, agg8, N);
    gemm_mfma_kernel<true><<<gemmBlocks, 256, 0, stream>>>(agg8, wbt, b1, dinv, hs8A, nullptr, N);
    // L2
    agg_kernel<<<aggBlocks, 256, 0, stream>>>(hs8A, dinv, rowp, colx, agg8, N);
    gemm_mfma_kernel<true><<<gemmBlocks, 256, 0, stream>>>(agg8, wbt + 16384, b2, dinv, hs8A, nullptr, N);
    // L3: gather -> agg8; gemm -> bf16 h3
    agg_kernel<<<aggBlocks, 256, 0, stream>>>(hs8A, dinv, rowp, colx, agg8, N);
    gemm_mfma_kernel<false><<<gemmBlocks, 256, 0, stream>>>(agg8, wbt + 32768, b3, dinv, nullptr, h3bf, N);

    pool_head_kernel<<<G, 512, 0, stream>>>(h3bf, batch, N, Wo, bo, (float*)d_out, G);
}

// Round 15
// 277.821 us; speedup vs baseline: 2.1059x; 1.0119x over previous
//
#include <hip/hip_runtime.h>
#include <hip/hip_bf16.h>
#include <stdint.h>

#define FDIM 128
#define CDIM 10

typedef unsigned short u16;
typedef unsigned char u8;
typedef __attribute__((ext_vector_type(8))) short short8;   // 8 bf16 (4 VGPRs) — MFMA A/B frag
typedef __attribute__((ext_vector_type(4))) float f32x4;    // MFMA C/D frag
typedef __attribute__((ext_vector_type(2))) float f32x2;

__device__ inline u16 f2bf(float f) {
    unsigned int u = __float_as_uint(f);
    u += 0x7fff + ((u >> 16) & 1);  // round-to-nearest-even
    return (u16)(u >> 16);
}
__device__ inline unsigned int pack2(float a, float b) {
    return (unsigned int)f2bf(a) | ((unsigned int)f2bf(b) << 16);
}
// accumulate 4 fp8 (one uint) into two f32x2 accs via hw cvt
__device__ inline void acc_fp8x4(f32x2& a0, f32x2& a1, unsigned u) {
    a0 += __builtin_amdgcn_cvt_pk_f32_fp8(u, false);
    a1 += __builtin_amdgcn_cvt_pk_f32_fp8(u, true);
}
// pack 4 f32 -> 4 fp8 bytes (one uint)
__device__ inline unsigned pk_fp8x4(float a, float b, float c, float d) {
    unsigned o = 0;
    o = __builtin_amdgcn_cvt_pk_fp8_f32(a, b, o, false);
    o = __builtin_amdgcn_cvt_pk_fp8_f32(c, d, o, true);
    return o;
}

// ---------------- utility ----------------

__global__ void sentinel_kernel(float* __restrict__ out, int n, float val) {
    int i = blockIdx.x * blockDim.x + threadIdx.x;
    if (i < n) out[i] = val;
}

// blocks 0..191: W[128][128] fp32 -> WbT[n][k] bf16 for 3 matrices
// block 192: zero row N of fp8 table; block 193: zero bcnt
__global__ void wconv_kernel(const float* __restrict__ W1, const float* __restrict__ W2,
                             const float* __restrict__ W3, u16* __restrict__ wbt,
                             unsigned* __restrict__ hs8A_rowN, int* __restrict__ bcnt, int NB) {
    int tid = threadIdx.x;
    if (blockIdx.x == 192) {
        if (tid < FDIM / 4) hs8A_rowN[tid] = 0;
        return;
    }
    if (blockIdx.x == 193) {
        for (int i = tid; i < NB; i += 256) bcnt[i] = 0;
        return;
    }
    int which = blockIdx.x >> 6;
    int i = (blockIdx.x & 63) * 256 + tid;
    const float* W = which == 0 ? W1 : (which == 1 ? W2 : W3);
    int k = i >> 7, n = i & 127;
    wbt[(size_t)which * 16384 + n * 128 + k] = f2bf(W[k * 128 + n]);
}

// x fp32 -> fp8 pre-scaled by dinv (4 elems/thread)
__global__ void xconv_kernel(const float* __restrict__ x, const float* __restrict__ dinv,
                             u8* __restrict__ hs8A, int N) {
    int i = (blockIdx.x * blockDim.x + threadIdx.x) * 4;
    if (i < N * FDIM) {
        int v = i >> 7;
        float dv = dinv[v];
        float4 f = *(const float4*)&x[i];
        ((unsigned*)hs8A)[i >> 2] = pk_fp8x4(dv * f.x, dv * f.y, dv * f.z, dv * f.w);
    }
}

// ---------------- bucketed CSR build (256-node buckets — R10 proven config) ----------------
// b = dst >> 8.  NB = ceil(N/256) <= 512.
// ebuf entry packed: (dst & 255) << 24 | src   (requires N <= 2^24)

#define ECHUNK 4096

__global__ __launch_bounds__(256) void count_kernel(const int* __restrict__ dst, int E,
                                                    int* __restrict__ bcnt, int NB) {
    __shared__ int lc[512];
    int tid = threadIdx.x;
    for (int i = tid; i < NB; i += 256) lc[i] = 0;
    __syncthreads();
    int base = blockIdx.x * ECHUNK;
    int lim = min(base + ECHUNK, E);
    for (int i = base + tid; i < lim; i += 256)
        atomicAdd(&lc[dst[i] >> 8], 1);
    __syncthreads();
    for (int i = tid; i < NB; i += 256)
        if (lc[i]) atomicAdd(&bcnt[i], lc[i]);
}

__global__ __launch_bounds__(512) void scan_kernel(const int* __restrict__ bcnt, int NB, int E,
                                                   int* __restrict__ boff, int* __restrict__ bcursor) {
    __shared__ int s[512];
    int tid = threadIdx.x;
    s[tid] = (tid < NB) ? bcnt[tid] : 0;
    __syncthreads();
    for (int off = 1; off < 512; off <<= 1) {
        int v = (tid >= off) ? s[tid - off] : 0;
        __syncthreads();
        s[tid] += v;
        __syncthreads();
    }
    int excl = tid ? s[tid - 1] : 0;
    if (tid < NB) { boff[tid] = excl; bcursor[tid] = excl; }
    if (tid == 0) boff[NB] = E;
}

__global__ __launch_bounds__(256) void part_kernel(const int* __restrict__ src,
                                                   const int* __restrict__ dst, int E,
                                                   int* __restrict__ bcursor,
                                                   unsigned* __restrict__ ebuf, int NB) {
    __shared__ int lc[512];
    __shared__ int lbase[512];
    int tid = threadIdx.x;
    for (int i = tid; i < NB; i += 256) lc[i] = 0;
    __syncthreads();
    int base = blockIdx.x * ECHUNK;
    int lim = min(base + ECHUNK, E);
    for (int i = base + tid; i < lim; i += 256)
        atomicAdd(&lc[dst[i] >> 8], 1);
    __syncthreads();
    for (int i = tid; i < NB; i += 256) {
        int c = lc[i];
        lbase[i] = c ? atomicAdd(&bcursor[i], c) : 0;
        lc[i] = 0;  // reuse as local cursor
    }
    __syncthreads();
    for (int i = base + tid; i < lim; i += 256) {
        int s_ = src[i];
        int d_ = dst[i];
        int b = d_ >> 8;
        int r = atomicAdd(&lc[b], 1);
        ebuf[lbase[b] + r] = ((unsigned)(d_ & 255) << 24) | (unsigned)s_;
    }
}

// one block per 256-node bucket: hist -> scan -> rowp/dinv; scatter colx in bucket window
__global__ __launch_bounds__(256) void build_kernel(const unsigned* __restrict__ ebuf,
                                                    const int* __restrict__ boff,
                                                    int* __restrict__ rowp, float* __restrict__ dinv,
                                                    int* __restrict__ colx, int N, int E) {
    __shared__ int hist[256];
    __shared__ int pfx[256];
    __shared__ int cur[256];
    int b = blockIdx.x;
    int tid = threadIdx.x;
    int ebase = boff[b], eend = boff[b + 1];
    hist[tid] = 0;
    __syncthreads();
    for (int i = ebase + tid; i < eend; i += 256)
        atomicAdd(&hist[ebuf[i] >> 24], 1);
    __syncthreads();
    int deg = hist[tid];
    pfx[tid] = deg;
    __syncthreads();
    for (int off = 1; off < 256; off <<= 1) {
        int t = (tid >= off) ? pfx[tid - off] : 0;
        __syncthreads();
        pfx[tid] += t;
        __syncthreads();
    }
    int excl = pfx[tid] - deg;
    int node = b * 256 + tid;
    if (node < N) {
        rowp[node] = ebase + excl;
        dinv[node] = rsqrtf(1.0f + (float)deg);  // +1 self-loop
        if (node == N - 1) rowp[N] = E;
    }
    cur[tid] = ebase + excl;
    __syncthreads();
    for (int i = ebase + tid; i < eend; i += 256) {
        unsigned e = ebuf[i];
        int r = atomicAdd(&cur[e >> 24], 1);
        colx[r] = (int)(e & 0xFFFFFFu);
    }
}

// ---------------- aggregation: node-per-group, unroll 8 (8 row-gathers in flight) ----------------
// lane = 8*g + c: group g owns node v = blk*32 + wave*8 + g; its 8 lanes cover the
// 128-fp8 row (16B each). Tail edges clamp to zero row N (L1-hot).
// out8[v] = fp8(dinv[v]*(hs8[v] + sum_u hs8[u])).

__global__ __launch_bounds__(256) void agg_kernel(const u8* __restrict__ hs8,
                                                  const float* __restrict__ dinv,
                                                  const int* __restrict__ rowp,
                                                  const int* __restrict__ colx,
                                                  u8* __restrict__ out8, int N) {
    int tid = threadIdx.x;
    int lane = tid & 63;
    int g = lane >> 3;   // 0..7: node slot
    int c = lane & 7;    // 0..7: 16B chunk within row
    int v = blockIdx.x * 32 + (tid >> 6) * 8 + g;
    bool valid = v < N;
    int vv = valid ? v : N;  // clamp to zero row

    const uint4* h4 = (const uint4*)hs8;  // row = 8 uint4
    f32x2 acc[8];
    uint4 s = h4[(size_t)vv * 8 + c];
#pragma unroll
    for (int j = 0; j < 8; ++j) acc[j] = (f32x2){0.f, 0.f};
    acc_fp8x4(acc[0], acc[1], s.x); acc_fp8x4(acc[2], acc[3], s.y);
    acc_fp8x4(acc[4], acc[5], s.z); acc_fp8x4(acc[6], acc[7], s.w);

    int e = valid ? rowp[v] : 0;
    int end = valid ? rowp[v + 1] : 0;
    for (; e < end; e += 8) {
        int u_[8];
#pragma unroll
        for (int j = 0; j < 8; ++j) {
            int ij = min(e + j, end - 1);
            u_[j] = (e + j < end) ? colx[ij] : N;
        }
        uint4 r_[8];
#pragma unroll
        for (int j = 0; j < 8; ++j) r_[j] = h4[(size_t)u_[j] * 8 + c];
#pragma unroll
        for (int j = 0; j < 8; ++j) {
            acc_fp8x4(acc[0], acc[1], r_[j].x); acc_fp8x4(acc[2], acc[3], r_[j].y);
            acc_fp8x4(acc[4], acc[5], r_[j].z); acc_fp8x4(acc[6], acc[7], r_[j].w);
        }
    }

    if (valid) {
        float dv = dinv[v];
        uint4 o;
        o.x = pk_fp8x4(dv * acc[0].x, dv * acc[0].y, dv * acc[1].x, dv * acc[1].y);
        o.y = pk_fp8x4(dv * acc[2].x, dv * acc[2].y, dv * acc[3].x, dv * acc[3].y);
        o.z = pk_fp8x4(dv * acc[4].x, dv * acc[4].y, dv * acc[5].x, dv * acc[5].y);
        o.w = pk_fp8x4(dv * acc[6].x, dv * acc[6].y, dv * acc[7].x, dv * acc[7].y);
        ((uint4*)out8)[(size_t)v * 8 + c] = o;
    }
}

// ---------------- MFMA GEMM: reads fp8 agg buffer; writes fp8 table (in-place safe:
// reads only in8) or bf16 h3 (layer 3). Single barrier; wave-local LDS afterwards.
// fp8 epilogue staging ALIASES As (u8 rows, stride 272B) — each wave touches only its
// own 16 rows after the barrier, and u8 aliasing is TBAA-safe, so no extra LDS needed. ----

template <bool FP8OUT>
__global__ __launch_bounds__(256) void gemm_mfma_kernel(const u8* __restrict__ in8,
                                                        const u16* __restrict__ WbT,
                                                        const float* __restrict__ bias,
                                                        const float* __restrict__ dinv,
                                                        u8* __restrict__ out8,
                                                        u16* __restrict__ outbf, int N) {
    __shared__ u16 As[64][136];  // 17.4 KB total LDS -> 9 blocks/CU
    int tid = threadIdx.x;
    int w = tid >> 6;
    int l = tid & 63;
    int row0 = blockIdx.x * 64;

    // stage A tile: 64 rows x 128 fp8 = 512 chunks of 16B; thread converts 2 -> bf16 LDS
#pragma unroll
    for (int i = 0; i < 2; ++i) {
        int ch = tid + 256 * i;
        int r = ch >> 3;
        int cc = ch & 7;
        uint4 val = make_uint4(0, 0, 0, 0);
        if (row0 + r < N) val = ((const uint4*)(in8 + (size_t)(row0 + r) * FDIM))[cc];
        f32x2 f0 = __builtin_amdgcn_cvt_pk_f32_fp8(val.x, false);
        f32x2 f1 = __builtin_amdgcn_cvt_pk_f32_fp8(val.x, true);
        f32x2 f2 = __builtin_amdgcn_cvt_pk_f32_fp8(val.y, false);
        f32x2 f3 = __builtin_amdgcn_cvt_pk_f32_fp8(val.y, true);
        f32x2 f4 = __builtin_amdgcn_cvt_pk_f32_fp8(val.z, false);
        f32x2 f5 = __builtin_amdgcn_cvt_pk_f32_fp8(val.z, true);
        f32x2 f6 = __builtin_amdgcn_cvt_pk_f32_fp8(val.w, false);
        f32x2 f7 = __builtin_amdgcn_cvt_pk_f32_fp8(val.w, true);
        uint4 o0, o1;
        o0.x = pack2(f0.x, f0.y); o0.y = pack2(f1.x, f1.y);
        o0.z = pack2(f2.x, f2.y); o0.w = pack2(f3.x, f3.y);
        o1.x = pack2(f4.x, f4.y); o1.y = pack2(f5.x, f5.y);
        o1.z = pack2(f6.x, f6.y); o1.w = pack2(f7.x, f7.y);
        *(uint4*)&As[r][cc * 16] = o0;
        *(uint4*)&As[r][cc * 16 + 8] = o1;
    }
    __syncthreads();  // the only barrier

    int arow = w * 16 + (l & 15);
    int kblk = (l >> 4) * 8;
    f32x4 facc[8];
#pragma unroll
    for (int f = 0; f < 8; ++f) facc[f] = (f32x4){0.f, 0.f, 0.f, 0.f};

#pragma unroll
    for (int kk = 0; kk < 4; ++kk) {
        int k0 = kk * 32 + kblk;
        short8 a = *(const short8*)&As[arow][k0];
#pragma unroll
        for (int f = 0; f < 8; ++f) {
            int col = f * 16 + (l & 15);
            short8 bfr = *(const short8*)&WbT[(size_t)col * FDIM + k0];
            facc[f] = __builtin_amdgcn_mfma_f32_16x16x32_bf16(a, bfr, facc[f], 0, 0, 0);
        }
    }

    int rbase = w * 16 + (l >> 4) * 4;
    int cidx = l & 15;

    if constexpr (FP8OUT) {
        float dvr[4];
#pragma unroll
        for (int r = 0; r < 4; ++r) {
            int row = row0 + rbase + r;
            dvr[r] = (row < N) ? dinv[row] : 1.f;
        }
        // fp8 staging aliased into As rows (u8, row stride 272B) — wave-local rows only
        u8* As8 = (u8*)&As[0][0];
#pragma unroll
        for (int f = 0; f < 8; ++f) {
            int col = f * 16 + cidx;
            float bv = bias[col];
#pragma unroll
            for (int r = 0; r < 4; ++r) {
                float val = dvr[r] * fmaxf(facc[f][r] + bv, 0.f);
                unsigned pk = __builtin_amdgcn_cvt_pk_fp8_f32(val, 0.f, 0, false);
                As8[(rbase + r) * 272 + col] = (u8)(pk & 0xff);
            }
        }
        // wave-local coalesced store: 16 rows x 128B = 2 iters x 64 lanes x 16B
#pragma unroll
        for (int i = 0; i < 2; ++i) {
            int flat = i * 64 + l;
            int r = w * 16 + (flat >> 3);
            int ch = flat & 7;
            if (row0 + r < N)
                ((uint4*)(out8 + (size_t)(row0 + r) * FDIM))[ch] = *(const uint4*)&As8[r * 272 + ch * 16];
        }
    } else {
        // epilogue: relu(acc+b) -> bf16 into As (wave-local), coalesced store to outbf
#pragma unroll
        for (int f = 0; f < 8; ++f) {
            int col = f * 16 + cidx;
            float bv = bias[col];
#pragma unroll
            for (int r = 0; r < 4; ++r)
                As[rbase + r][col] = f2bf(fmaxf(facc[f][r] + bv, 0.f));
        }
#pragma unroll
        for (int i = 0; i < 4; ++i) {
            int r = w * 16 + (l >> 4) * 4 + i;
            int col = (l & 15) * 8;
            if (row0 + r < N) *(uint4*)&outbf[(size_t)(row0 + r) * FDIM + col] = *(const uint4*)&As[r][col];
        }
    }
}

// ---------------- pooling + classifier head + log_softmax ----------------

__global__ __launch_bounds__(512) void pool_head_kernel(const u16* __restrict__ h,
                                                        const int* __restrict__ batch, int N,
                                                        const float* __restrict__ Wo,
                                                        const float* __restrict__ bo,
                                                        float* __restrict__ out, int G) {
    int g = blockIdx.x;
    int tid = threadIdx.x;
    __shared__ int bounds[2];
    __shared__ float2 red[512];
    __shared__ float sp[128];
    __shared__ float lg[CDIM];
    __shared__ float sm[2];

    if (tid < 2) {
        int target = g + tid;
        int lo = 0, hi = N;
        while (lo < hi) {
            int mid = (lo + hi) >> 1;
            if (batch[mid] < target) lo = mid + 1; else hi = mid;
        }
        bounds[tid] = lo;
    }
    __syncthreads();
    int lo = bounds[0], hi = bounds[1];
    int cnt = hi - lo;

    int j = tid & 63;
    int rg = tid >> 6;
    const unsigned* h2 = (const unsigned*)h;
    float ax = 0.f, ay = 0.f;
    for (int r = lo + rg; r < hi; r += 8) {
        unsigned u = h2[(size_t)r * 64 + j];
        ax += __uint_as_float(u << 16);
        ay += __uint_as_float(u & 0xffff0000u);
    }
    red[tid] = make_float2(ax, ay);
    __syncthreads();
    if (tid < 64) {
        float sx = 0.f, sy = 0.f;
#pragma unroll
        for (int k = 0; k < 8; ++k) {
            float2 t = red[tid + 64 * k];
            sx += t.x; sy += t.y;
        }
        float inv = 1.f / (float)max(cnt, 1);
        sp[2 * tid] = sx * inv;
        sp[2 * tid + 1] = sy * inv;
    }
    __syncthreads();

    if (tid < CDIM) {
        float l = bo[tid];
        for (int k = 0; k < 128; ++k) l += sp[k] * Wo[(size_t)k * CDIM + tid];
        lg[tid] = l;
    }
    __syncthreads();
    if (tid == 0) {
        float m = -1e30f;
        for (int c = 0; c < CDIM; ++c) m = fmaxf(m, lg[c]);
        float ssum = 0.f;
        for (int c = 0; c < CDIM; ++c) ssum += expf(lg[c] - m);
        sm[0] = m;
        sm[1] = logf(ssum);
    }
    __syncthreads();
    if (tid < CDIM) out[(size_t)g * CDIM + tid] = lg[tid] - sm[0] - sm[1];
}

// ---------------- launch ----------------

extern "C" void kernel_launch(void* const* d_in, const int* in_sizes, int n_in,
                              void* d_out, int out_size, void* d_ws, size_t ws_size,
                              hipStream_t stream) {
    const float* x = (const float*)d_in[0];
    const int* edge = (const int*)d_in[1];      // int32 (harness converts integer inputs)
    const int* batch = (const int*)d_in[2];     // int32
    const float* W1 = (const float*)d_in[4];
    const float* b1 = (const float*)d_in[5];
    const float* W2 = (const float*)d_in[6];
    const float* b2 = (const float*)d_in[7];
    const float* W3 = (const float*)d_in[8];
    const float* b3 = (const float*)d_in[9];
    const float* Wo = (const float*)d_in[10];
    const float* bo = (const float*)d_in[11];

    int N = in_sizes[2];
    int E = in_sizes[1] / 2;
    int G = out_size / CDIM;
    const int* src = edge;
    const int* dst = edge + E;
    int NB = (N + 255) >> 8;   // 256-node buckets

    size_t off = 0;
    auto carve = [&](size_t bytes) -> size_t {
        size_t r = off;
        off += (bytes + 255) & ~(size_t)255;
        return r;
    };
    size_t o_h3   = carve((size_t)N * FDIM * 2);          // bf16 h3 (ebuf aliases here)
    size_t o_hs8A = carve((size_t)(N + 1) * FDIM);        // fp8 gather table (row N = zeros)
    size_t o_agg8 = carve((size_t)N * FDIM);              // fp8 agg output
    size_t o_colx = carve((size_t)E * 4);
    size_t o_rowp = carve((size_t)(N + 1) * 4);
    size_t o_dinv = carve((size_t)N * 4);
    size_t o_bcnt = carve((size_t)NB * 4);
    size_t o_boff = carve((size_t)(NB + 1) * 4);
    size_t o_bcur = carve((size_t)NB * 4);
    size_t o_wbt  = carve((size_t)3 * 16384 * 2);

    bool ok = off <= ws_size && NB <= 512 && N <= (1 << 24) &&
              (size_t)E * 4 <= (size_t)N * FDIM * 2;  // packed ebuf fits in h3 alias
    if (!ok) {
        sentinel_kernel<<<(out_size + 255) / 256, 256, 0, stream>>>((float*)d_out, out_size, 1234.5f);
        return;
    }

    char* base = (char*)d_ws;
    u16* h3bf  = (u16*)(base + o_h3);
    u8* hs8A   = (u8*)(base + o_hs8A);
    u8* agg8   = (u8*)(base + o_agg8);
    unsigned* ebuf = (unsigned*)(base + o_h3);  // alias: dead after build_kernel; h3 written by L3 gemm
    int* colx  = (int*)(base + o_colx);
    int* rowp  = (int*)(base + o_rowp);
    float* dinv = (float*)(base + o_dinv);
    int* bcnt  = (int*)(base + o_bcnt);
    int* boff  = (int*)(base + o_boff);
    int* bcur  = (int*)(base + o_bcur);
    u16* wbt   = (u16*)(base + o_wbt);

    int nchunk = (E + ECHUNK - 1) / ECHUNK;

    wconv_kernel<<<194, 256, 0, stream>>>(W1, W2, W3, wbt,
                                          (unsigned*)(hs8A + (size_t)N * FDIM), bcnt, NB);
    count_kernel<<<nchunk, 256, 0, stream>>>(dst, E, bcnt, NB);
    scan_kernel<<<1, 512, 0, stream>>>(bcnt, NB, E, boff, bcur);
    part_kernel<<<nchunk, 256, 0, stream>>>(src, dst, E, bcur, ebuf, NB);
    build_kernel<<<NB, 256, 0, stream>>>(ebuf, boff, rowp, dinv, colx, N, E);
    xconv_kernel<<<(N * FDIM / 4 + 255) / 256, 256, 0, stream>>>(x, dinv, hs8A, N);

    int aggBlocks = (N + 31) / 32;
    int gemmBlocks = (N + 63) / 64;

    // L1: gather hs8A -> agg8; gemm reads agg8 -> overwrites hs8A (next table)
    agg_kernel<<<aggBlocks, 256, 0, stream>>>(hs8A, dinv, rowp, colx, agg8, N);
    gemm_mfma_kernel<true><<<gemmBlocks, 256, 0, stream>>>(agg8, wbt, b1, dinv, hs8A, nullptr, N);
    // L2
    agg_kernel<<<aggBlocks, 256, 0, stream>>>(hs8A, dinv, rowp, colx, agg8, N);
    gemm_mfma_kernel<true><<<gemmBlocks, 256, 0, stream>>>(agg8, wbt + 16384, b2, dinv, hs8A, nullptr, N);
    // L3: gather -> agg8; gemm -> bf16 h3
    agg_kernel<<<aggBlocks, 256, 0, stream>>>(hs8A, dinv, rowp, colx, agg8, N);
    gemm_mfma_kernel<false><<<gemmBlocks, 256, 0, stream>>>(agg8, wbt + 32768, b3, dinv, nullptr, h3bf, N);

    pool_head_kernel<<<G, 512, 0, stream>>>(h3bf, batch, N, Wo, bo, (float*)d_out, G);
}

// Round 16
// 272.099 us; speedup vs baseline: 2.1502x; 1.0210x over previous
//
#include <hip/hip_runtime.h>
#include <hip/hip_bf16.h>
#include <stdint.h>

#define FDIM 128
#define CDIM 10

typedef unsigned short u16;
typedef unsigned char u8;
typedef __attribute__((ext_vector_type(8))) short short8;   // 8 bf16 (4 VGPRs) — MFMA A/B frag
typedef __attribute__((ext_vector_type(4))) float f32x4;    // MFMA C/D frag
typedef __attribute__((ext_vector_type(2))) float f32x2;

__device__ inline u16 f2bf(float f) {
    unsigned int u = __float_as_uint(f);
    u += 0x7fff + ((u >> 16) & 1);  // round-to-nearest-even
    return (u16)(u >> 16);
}
__device__ inline unsigned int pack2(float a, float b) {
    return (unsigned int)f2bf(a) | ((unsigned int)f2bf(b) << 16);
}
// accumulate 4 fp8 (one uint) into two f32x2 accs via hw cvt
__device__ inline void acc_fp8x4(f32x2& a0, f32x2& a1, unsigned u) {
    a0 += __builtin_amdgcn_cvt_pk_f32_fp8(u, false);
    a1 += __builtin_amdgcn_cvt_pk_f32_fp8(u, true);
}
// pack 4 f32 -> 4 fp8 bytes (one uint)
__device__ inline unsigned pk_fp8x4(float a, float b, float c, float d) {
    unsigned o = 0;
    o = __builtin_amdgcn_cvt_pk_fp8_f32(a, b, o, false);
    o = __builtin_amdgcn_cvt_pk_fp8_f32(c, d, o, true);
    return o;
}

// ---------------- utility ----------------

__global__ void sentinel_kernel(float* __restrict__ out, int n, float val) {
    int i = blockIdx.x * blockDim.x + threadIdx.x;
    if (i < n) out[i] = val;
}

// blocks 0..191: W[128][128] fp32 -> WbT[n][k] bf16 for 3 matrices
// block 192: zero row N of fp8 table; block 193: zero bcnt
__global__ void wconv_kernel(const float* __restrict__ W1, const float* __restrict__ W2,
                             const float* __restrict__ W3, u16* __restrict__ wbt,
                             unsigned* __restrict__ hs8A_rowN, int* __restrict__ bcnt, int NB) {
    int tid = threadIdx.x;
    if (blockIdx.x == 192) {
        if (tid < FDIM / 4) hs8A_rowN[tid] = 0;
        return;
    }
    if (blockIdx.x == 193) {
        for (int i = tid; i < NB; i += 256) bcnt[i] = 0;
        return;
    }
    int which = blockIdx.x >> 6;
    int i = (blockIdx.x & 63) * 256 + tid;
    const float* W = which == 0 ? W1 : (which == 1 ? W2 : W3);
    int k = i >> 7, n = i & 127;
    wbt[(size_t)which * 16384 + n * 128 + k] = f2bf(W[k * 128 + n]);
}

// x fp32 -> fp8 pre-scaled by dinv (4 elems/thread)
__global__ void xconv_kernel(const float* __restrict__ x, const float* __restrict__ dinv,
                             u8* __restrict__ hs8A, int N) {
    int i = (blockIdx.x * blockDim.x + threadIdx.x) * 4;
    if (i < N * FDIM) {
        int v = i >> 7;
        float dv = dinv[v];
        float4 f = *(const float4*)&x[i];
        ((unsigned*)hs8A)[i >> 2] = pk_fp8x4(dv * f.x, dv * f.y, dv * f.z, dv * f.w);
    }
}

// ---------------- bucketed CSR build (256-node buckets; 512-thread blocks) ----------------
// b = dst >> 8.  NB = ceil(N/256) <= 512.
// ebuf entry packed: (dst & 255) << 24 | src   (requires N <= 2^24)

#define ECHUNK 4096

__global__ __launch_bounds__(512) void count_kernel(const int* __restrict__ dst, int E,
                                                    int* __restrict__ bcnt, int NB) {
    __shared__ int lc[512];
    int tid = threadIdx.x;
    if (tid < NB) lc[tid] = 0;
    __syncthreads();
    int base = blockIdx.x * ECHUNK;
    int lim = min(base + ECHUNK, E);
    for (int i = base + tid; i < lim; i += 512)
        atomicAdd(&lc[dst[i] >> 8], 1);
    __syncthreads();
    if (tid < NB && lc[tid]) atomicAdd(&bcnt[tid], lc[tid]);
}

__global__ __launch_bounds__(512) void scan_kernel(const int* __restrict__ bcnt, int NB, int E,
                                                   int* __restrict__ boff, int* __restrict__ bcursor) {
    __shared__ int s[512];
    int tid = threadIdx.x;
    s[tid] = (tid < NB) ? bcnt[tid] : 0;
    __syncthreads();
    for (int off = 1; off < 512; off <<= 1) {
        int v = (tid >= off) ? s[tid - off] : 0;
        __syncthreads();
        s[tid] += v;
        __syncthreads();
    }
    int excl = tid ? s[tid - 1] : 0;
    if (tid < NB) { boff[tid] = excl; bcursor[tid] = excl; }
    if (tid == 0) boff[NB] = E;
}

__global__ __launch_bounds__(512) void part_kernel(const int* __restrict__ src,
                                                   const int* __restrict__ dst, int E,
                                                   int* __restrict__ bcursor,
                                                   unsigned* __restrict__ ebuf, int NB) {
    __shared__ int lc[512];
    __shared__ int lbase[512];
    int tid = threadIdx.x;
    if (tid < NB) lc[tid] = 0;
    __syncthreads();
    int base = blockIdx.x * ECHUNK;
    int lim = min(base + ECHUNK, E);
    for (int i = base + tid; i < lim; i += 512)
        atomicAdd(&lc[dst[i] >> 8], 1);
    __syncthreads();
    if (tid < NB) {
        int c = lc[tid];
        lbase[tid] = c ? atomicAdd(&bcursor[tid], c) : 0;
        lc[tid] = 0;  // reuse as local cursor
    }
    __syncthreads();
    for (int i = base + tid; i < lim; i += 512) {
        int s_ = src[i];
        int d_ = dst[i];
        int b = d_ >> 8;
        int r = atomicAdd(&lc[b], 1);
        ebuf[lbase[b] + r] = ((unsigned)(d_ & 255) << 24) | (unsigned)s_;
    }
}

// one block per 256-node bucket (512 thr): hist -> scan -> rowp/dinv; scatter colx
__global__ __launch_bounds__(512) void build_kernel(const unsigned* __restrict__ ebuf,
                                                    const int* __restrict__ boff,
                                                    int* __restrict__ rowp, float* __restrict__ dinv,
                                                    int* __restrict__ colx, int N, int E) {
    __shared__ int hist[256];
    __shared__ int pfx[256];
    __shared__ int cur[256];
    int b = blockIdx.x;
    int tid = threadIdx.x;
    int ebase = boff[b], eend = boff[b + 1];
    if (tid < 256) hist[tid] = 0;
    __syncthreads();
    for (int i = ebase + tid; i < eend; i += 512)
        atomicAdd(&hist[ebuf[i] >> 24], 1);
    __syncthreads();
    if (tid < 256) pfx[tid] = hist[tid];
    __syncthreads();
    for (int off = 1; off < 256; off <<= 1) {
        int t = 0;
        if (tid < 256 && tid >= off) t = pfx[tid - off];
        __syncthreads();
        if (tid < 256) pfx[tid] += t;
        __syncthreads();
    }
    if (tid < 256) {
        int deg = hist[tid];
        int excl = pfx[tid] - deg;
        int node = b * 256 + tid;
        if (node < N) {
            rowp[node] = ebase + excl;
            dinv[node] = rsqrtf(1.0f + (float)deg);  // +1 self-loop
            if (node == N - 1) rowp[N] = E;
        }
        cur[tid] = ebase + excl;
    }
    __syncthreads();
    for (int i = ebase + tid; i < eend; i += 512) {
        unsigned e = ebuf[i];
        int r = atomicAdd(&cur[e >> 24], 1);
        colx[r] = (int)(e & 0xFFFFFFu);
    }
}

// ---------------- aggregation: node-per-group, unroll 8 (8 row-gathers in flight) ----------------
// lane = 8*g + c: group g owns node v = blk*32 + wave*8 + g; its 8 lanes cover the
// 128-fp8 row (16B each). Tail edges clamp to zero row N (L1-hot).
// out8[v] = fp8(dinv[v]*(hs8[v] + sum_u hs8[u])).

__global__ __launch_bounds__(256) void agg_kernel(const u8* __restrict__ hs8,
                                                  const float* __restrict__ dinv,
                                                  const int* __restrict__ rowp,
                                                  const int* __restrict__ colx,
                                                  u8* __restrict__ out8, int N) {
    int tid = threadIdx.x;
    int lane = tid & 63;
    int g = lane >> 3;   // 0..7: node slot
    int c = lane & 7;    // 0..7: 16B chunk within row
    int v = blockIdx.x * 32 + (tid >> 6) * 8 + g;
    bool valid = v < N;
    int vv = valid ? v : N;  // clamp to zero row

    const uint4* h4 = (const uint4*)hs8;  // row = 8 uint4
    f32x2 acc[8];
    uint4 s = h4[(size_t)vv * 8 + c];
#pragma unroll
    for (int j = 0; j < 8; ++j) acc[j] = (f32x2){0.f, 0.f};
    acc_fp8x4(acc[0], acc[1], s.x); acc_fp8x4(acc[2], acc[3], s.y);
    acc_fp8x4(acc[4], acc[5], s.z); acc_fp8x4(acc[6], acc[7], s.w);

    int e = valid ? rowp[v] : 0;
    int end = valid ? rowp[v + 1] : 0;
    for (; e < end; e += 8) {
        int u_[8];
#pragma unroll
        for (int j = 0; j < 8; ++j) {
            int ij = min(e + j, end - 1);
            u_[j] = (e + j < end) ? colx[ij] : N;
        }
        uint4 r_[8];
#pragma unroll
        for (int j = 0; j < 8; ++j) r_[j] = h4[(size_t)u_[j] * 8 + c];
#pragma unroll
        for (int j = 0; j < 8; ++j) {
            acc_fp8x4(acc[0], acc[1], r_[j].x); acc_fp8x4(acc[2], acc[3], r_[j].y);
            acc_fp8x4(acc[4], acc[5], r_[j].z); acc_fp8x4(acc[6], acc[7], r_[j].w);
        }
    }

    if (valid) {
        float dv = dinv[v];
        uint4 o;
        o.x = pk_fp8x4(dv * acc[0].x, dv * acc[0].y, dv * acc[1].x, dv * acc[1].y);
        o.y = pk_fp8x4(dv * acc[2].x, dv * acc[2].y, dv * acc[3].x, dv * acc[3].y);
        o.z = pk_fp8x4(dv * acc[4].x, dv * acc[4].y, dv * acc[5].x, dv * acc[5].y);
        o.w = pk_fp8x4(dv * acc[6].x, dv * acc[6].y, dv * acc[7].x, dv * acc[7].y);
        ((uint4*)out8)[(size_t)v * 8 + c] = o;
    }
}

// ---------------- MFMA GEMM: reads fp8 agg buffer; writes fp8 table (in-place safe:
// reads only in8) or bf16 h3 (layer 3). Single barrier; wave-local LDS afterwards.
// fp8 epilogue staging ALIASES As (u8 rows, stride 272B) — wave-local rows only. ----

template <bool FP8OUT>
__global__ __launch_bounds__(256) void gemm_mfma_kernel(const u8* __restrict__ in8,
                                                        const u16* __restrict__ WbT,
                                                        const float* __restrict__ bias,
                                                        const float* __restrict__ dinv,
                                                        u8* __restrict__ out8,
                                                        u16* __restrict__ outbf, int N) {
    __shared__ u16 As[64][136];  // 17.4 KB total LDS
    int tid = threadIdx.x;
    int w = tid >> 6;
    int l = tid & 63;
    int row0 = blockIdx.x * 64;

    // stage A tile: 64 rows x 128 fp8 = 512 chunks of 16B; thread converts 2 -> bf16 LDS
#pragma unroll
    for (int i = 0; i < 2; ++i) {
        int ch = tid + 256 * i;
        int r = ch >> 3;
        int cc = ch & 7;
        uint4 val = make_uint4(0, 0, 0, 0);
        if (row0 + r < N) val = ((const uint4*)(in8 + (size_t)(row0 + r) * FDIM))[cc];
        f32x2 f0 = __builtin_amdgcn_cvt_pk_f32_fp8(val.x, false);
        f32x2 f1 = __builtin_amdgcn_cvt_pk_f32_fp8(val.x, true);
        f32x2 f2 = __builtin_amdgcn_cvt_pk_f32_fp8(val.y, false);
        f32x2 f3 = __builtin_amdgcn_cvt_pk_f32_fp8(val.y, true);
        f32x2 f4 = __builtin_amdgcn_cvt_pk_f32_fp8(val.z, false);
        f32x2 f5 = __builtin_amdgcn_cvt_pk_f32_fp8(val.z, true);
        f32x2 f6 = __builtin_amdgcn_cvt_pk_f32_fp8(val.w, false);
        f32x2 f7 = __builtin_amdgcn_cvt_pk_f32_fp8(val.w, true);
        uint4 o0, o1;
        o0.x = pack2(f0.x, f0.y); o0.y = pack2(f1.x, f1.y);
        o0.z = pack2(f2.x, f2.y); o0.w = pack2(f3.x, f3.y);
        o1.x = pack2(f4.x, f4.y); o1.y = pack2(f5.x, f5.y);
        o1.z = pack2(f6.x, f6.y); o1.w = pack2(f7.x, f7.y);
        *(uint4*)&As[r][cc * 16] = o0;
        *(uint4*)&As[r][cc * 16 + 8] = o1;
    }
    __syncthreads();  // the only barrier

    int arow = w * 16 + (l & 15);
    int kblk = (l >> 4) * 8;
    f32x4 facc[8];
#pragma unroll
    for (int f = 0; f < 8; ++f) facc[f] = (f32x4){0.f, 0.f, 0.f, 0.f};

#pragma unroll
    for (int kk = 0; kk < 4; ++kk) {
        int k0 = kk * 32 + kblk;
        short8 a = *(const short8*)&As[arow][k0];
#pragma unroll
        for (int f = 0; f < 8; ++f) {
            int col = f * 16 + (l & 15);
            short8 bfr = *(const short8*)&WbT[(size_t)col * FDIM + k0];
            facc[f] = __builtin_amdgcn_mfma_f32_16x16x32_bf16(a, bfr, facc[f], 0, 0, 0);
        }
    }

    int rbase = w * 16 + (l >> 4) * 4;
    int cidx = l & 15;

    if constexpr (FP8OUT) {
        float dvr[4];
#pragma unroll
        for (int r = 0; r < 4; ++r) {
            int row = row0 + rbase + r;
            dvr[r] = (row < N) ? dinv[row] : 1.f;
        }
        // fp8 staging aliased into As rows (u8, row stride 272B) — wave-local rows only
        u8* As8 = (u8*)&As[0][0];
#pragma unroll
        for (int f = 0; f < 8; ++f) {
            int col = f * 16 + cidx;
            float bv = bias[col];
#pragma unroll
            for (int r = 0; r < 4; ++r) {
                float val = dvr[r] * fmaxf(facc[f][r] + bv, 0.f);
                unsigned pk = __builtin_amdgcn_cvt_pk_fp8_f32(val, 0.f, 0, false);
                As8[(rbase + r) * 272 + col] = (u8)(pk & 0xff);
            }
        }
        // wave-local coalesced store: 16 rows x 128B = 2 iters x 64 lanes x 16B
#pragma unroll
        for (int i = 0; i < 2; ++i) {
            int flat = i * 64 + l;
            int r = w * 16 + (flat >> 3);
            int ch = flat & 7;
            if (row0 + r < N)
                ((uint4*)(out8 + (size_t)(row0 + r) * FDIM))[ch] = *(const uint4*)&As8[r * 272 + ch * 16];
        }
    } else {
        // epilogue: relu(acc+b) -> bf16 into As (wave-local), coalesced store to outbf
#pragma unroll
        for (int f = 0; f < 8; ++f) {
            int col = f * 16 + cidx;
            float bv = bias[col];
#pragma unroll
            for (int r = 0; r < 4; ++r)
                As[rbase + r][col] = f2bf(fmaxf(facc[f][r] + bv, 0.f));
        }
#pragma unroll
        for (int i = 0; i < 4; ++i) {
            int r = w * 16 + (l >> 4) * 4 + i;
            int col = (l & 15) * 8;
            if (row0 + r < N) *(uint4*)&outbf[(size_t)(row0 + r) * FDIM + col] = *(const uint4*)&As[r][col];
        }
    }
}

// ---------------- pooling + classifier head + log_softmax ----------------

__global__ __launch_bounds__(512) void pool_head_kernel(const u16* __restrict__ h,
                                                        const int* __restrict__ batch, int N,
                                                        const float* __restrict__ Wo,
                                                        const float* __restrict__ bo,
                                                        float* __restrict__ out, int G) {
    int g = blockIdx.x;
    int tid = threadIdx.x;
    __shared__ int bounds[2];
    __shared__ float2 red[512];
    __shared__ float sp[128];
    __shared__ float lg[CDIM];
    __shared__ float sm[2];

    if (tid < 2) {
        int target = g + tid;
        int lo = 0, hi = N;
        while (lo < hi) {
            int mid = (lo + hi) >> 1;
            if (batch[mid] < target) lo = mid + 1; else hi = mid;
        }
        bounds[tid] = lo;
    }
    __syncthreads();
    int lo = bounds[0], hi = bounds[1];
    int cnt = hi - lo;

    int j = tid & 63;
    int rg = tid >> 6;
    const unsigned* h2 = (const unsigned*)h;
    float ax = 0.f, ay = 0.f;
    for (int r = lo + rg; r < hi; r += 8) {
        unsigned u = h2[(size_t)r * 64 + j];
        ax += __uint_as_float(u << 16);
        ay += __uint_as_float(u & 0xffff0000u);
    }
    red[tid] = make_float2(ax, ay);
    __syncthreads();
    if (tid < 64) {
        float sx = 0.f, sy = 0.f;
#pragma unroll
        for (int k = 0; k < 8; ++k) {
            float2 t = red[tid + 64 * k];
            sx += t.x; sy += t.y;
        }
        float inv = 1.f / (float)max(cnt, 1);
        sp[2 * tid] = sx * inv;
        sp[2 * tid + 1] = sy * inv;
    }
    __syncthreads();

    if (tid < CDIM) {
        float l = bo[tid];
        for (int k = 0; k < 128; ++k) l += sp[k] * Wo[(size_t)k * CDIM + tid];
        lg[tid] = l;
    }
    __syncthreads();
    if (tid == 0) {
        float m = -1e30f;
        for (int c = 0; c < CDIM; ++c) m = fmaxf(m, lg[c]);
        float ssum = 0.f;
        for (int c = 0; c < CDIM; ++c) ssum += expf(lg[c] - m);
        sm[0] = m;
        sm[1] = logf(ssum);
    }
    __syncthreads();
    if (tid < CDIM) out[(size_t)g * CDIM + tid] = lg[tid] - sm[0] - sm[1];
}

// ---------------- launch ----------------

extern "C" void kernel_launch(void* const* d_in, const int* in_sizes, int n_in,
                              void* d_out, int out_size, void* d_ws, size_t ws_size,
                              hipStream_t stream) {
    const float* x = (const float*)d_in[0];
    const int* edge = (const int*)d_in[1];      // int32 (harness converts integer inputs)
    const int* batch = (const int*)d_in[2];     // int32
    const float* W1 = (const float*)d_in[4];
    const float* b1 = (const float*)d_in[5];
    const float* W2 = (const float*)d_in[6];
    const float* b2 = (const float*)d_in[7];
    const float* W3 = (const float*)d_in[8];
    const float* b3 = (const float*)d_in[9];
    const float* Wo = (const float*)d_in[10];
    const float* bo = (const float*)d_in[11];

    int N = in_sizes[2];
    int E = in_sizes[1] / 2;
    int G = out_size / CDIM;
    const int* src = edge;
    const int* dst = edge + E;
    int NB = (N + 255) >> 8;   // 256-node buckets

    size_t off = 0;
    auto carve = [&](size_t bytes) -> size_t {
        size_t r = off;
        off += (bytes + 255) & ~(size_t)255;
        return r;
    };
    size_t o_h3   = carve((size_t)N * FDIM * 2);          // bf16 h3 (ebuf aliases here)
    size_t o_hs8A = carve((size_t)(N + 1) * FDIM);        // fp8 gather table (row N = zeros)
    size_t o_agg8 = carve((size_t)N * FDIM);              // fp8 agg output
    size_t o_colx = carve((size_t)E * 4);
    size_t o_rowp = carve((size_t)(N + 1) * 4);
    size_t o_dinv = carve((size_t)N * 4);
    size_t o_bcnt = carve((size_t)NB * 4);
    size_t o_boff = carve((size_t)(NB + 1) * 4);
    size_t o_bcur = carve((size_t)NB * 4);
    size_t o_wbt  = carve((size_t)3 * 16384 * 2);

    bool ok = off <= ws_size && NB <= 512 && N <= (1 << 24) &&
              (size_t)E * 4 <= (size_t)N * FDIM * 2;  // packed ebuf fits in h3 alias
    if (!ok) {
        sentinel_kernel<<<(out_size + 255) / 256, 256, 0, stream>>>((float*)d_out, out_size, 1234.5f);
        return;
    }

    char* base = (char*)d_ws;
    u16* h3bf  = (u16*)(base + o_h3);
    u8* hs8A   = (u8*)(base + o_hs8A);
    u8* agg8   = (u8*)(base + o_agg8);
    unsigned* ebuf = (unsigned*)(base + o_h3);  // alias: dead after build_kernel; h3 written by L3 gemm
    int* colx  = (int*)(base + o_colx);
    int* rowp  = (int*)(base + o_rowp);
    float* dinv = (float*)(base + o_dinv);
    int* bcnt  = (int*)(base + o_bcnt);
    int* boff  = (int*)(base + o_boff);
    int* bcur  = (int*)(base + o_bcur);
    u16* wbt   = (u16*)(base + o_wbt);

    int nchunk = (E + ECHUNK - 1) / ECHUNK;

    wconv_kernel<<<194, 256, 0, stream>>>(W1, W2, W3, wbt,
                                          (unsigned*)(hs8A + (size_t)N * FDIM), bcnt, NB);
    count_kernel<<<nchunk, 512, 0, stream>>>(dst, E, bcnt, NB);
    scan_kernel<<<1, 512, 0, stream>>>(bcnt, NB, E, boff, bcur);
    part_kernel<<<nchunk, 512, 0, stream>>>(src, dst, E, bcur, ebuf, NB);
    build_kernel<<<NB, 512, 0, stream>>>(ebuf, boff, rowp, dinv, colx, N, E);
    xconv_kernel<<<(N * FDIM / 4 + 255) / 256, 256, 0, stream>>>(x, dinv, hs8A, N);

    int aggBlocks = (N + 31) / 32;
    int gemmBlocks = (N + 63) / 64;

    // L1: gather hs8A -> agg8; gemm reads agg8 -> overwrites hs8A (next table)
    agg_kernel<<<aggBlocks, 256, 0, stream>>>(hs8A, dinv, rowp, colx, agg8, N);
    gemm_mfma_kernel<true><<<gemmBlocks, 256, 0, stream>>>(agg8, wbt, b1, dinv, hs8A, nullptr, N);
    // L2
    agg_kernel<<<aggBlocks, 256, 0, stream>>>(hs8A, dinv, rowp, colx, agg8, N);
    gemm_mfma_kernel<true><<<gemmBlocks, 256, 0, stream>>>(agg8, wbt + 16384, b2, dinv, hs8A, nullptr, N);
    // L3: gather -> agg8; gemm -> bf16 h3
    agg_kernel<<<aggBlocks, 256, 0, stream>>>(hs8A, dinv, rowp, colx, agg8, N);
    gemm_mfma_kernel<false><<<gemmBlocks, 256, 0, stream>>>(agg8, wbt + 32768, b3, dinv, nullptr, h3bf, N);

    pool_head_kernel<<<G, 512, 0, stream>>>(h3bf, batch, N, Wo, bo, (float*)d_out, G);
}